// Round 13
// baseline (438.148 us; speedup 1.0000x reference)
//
#include <hip/hip_runtime.h>
#include <hip/hip_bf16.h>
#include <stdint.h>

#define NE 800000
#define NN 50000

// ---- weight region (float offsets). O_W2 / O_WN2 / O_WC1T hold TRANSPOSED weights.
#define O_W1   0          // We1  [129*64] row-major
#define O_B1   8256
#define O_W2   8320       // We2^T [64*64]
#define O_B2   12416
#define O_WC1  12480      // Wc1  [64*64] row-major (atomic-fallback scalar path)
#define O_BC1  16576
#define O_WC2  16640
#define O_BC2  16704
#define O_WN1  16768      // Wn1  [128*64] row-major
#define O_BN1  24960
#define O_WN2  25024      // Wn2^T [64*64]
#define O_BN2  29120
#define O_FLAG 29184      // int: 1 = tensors bf16, 0 = f32
#define O_WC1T 29248      // Wc1^T [64*64] (MFMA path)

// ---- per-node layer-1 precompute (fp32):
// Y[n][0:64]=h[n]@We1[0:64] + b1 (b1 folded), Y[n][64:128]=h[n]@We1[64:128]
#define O_Y    33344                    // float [NN*128]
#define Y_END  (O_Y + NN*128)

// ---- CSR layout. N_RC holds col-only (int[NE]); ef16/tr regions unused
// (agg fused into edge kernel) but kept in the layout for ws-size gating.
#define N_OFF   Y_END                   // int off[NN+1] (padded to 50008)
#define N_CNT   (N_OFF + 50008)         // int count/cursor[NN]
#define N_RC    (N_CNT + NN)            // int col[NE] by position
#define N_AGGH  (N_RC + 2*NE)           // float [NN*64]
#define N_SUMT  (N_AGGH + NN*64)        // float [NN*3]
#define N_EF16  (N_SUMT + NN*3 + 2)     // (unused since R14)
#define N_TR    (N_EF16 + NE*32)        // (unused since R14)
#define N_TOTAL (N_TR + NE*3)           // ~39.5M words ~ 158 MB (ws gate)

// ---- atomic fallback layout ----
#define F_AGGH  Y_END
#define F_SUMT  (F_AGGH + NN*64)
#define F_CNT   (F_SUMT + NN*3)
#define F_TOTAL (F_CNT + NN)

#define OUT_COORD (NN*64)
#define OUT_V     (NN*64 + NN*3)

typedef __attribute__((ext_vector_type(8))) short bf16x8;
typedef __attribute__((ext_vector_type(4))) short bf16x4;
typedef __attribute__((ext_vector_type(4))) float f32x4;

static __device__ __forceinline__ float bf2f(const __hip_bfloat16 x) { return __bfloat162float(x); }

template<bool B16>
static __device__ __forceinline__ float ldf(const void* p, size_t i) {
    if (B16) return __bfloat162float(((const __hip_bfloat16*)p)[i]);
    else     return ((const float*)p)[i];
}
template<bool B16>
static __device__ __forceinline__ void stf(void* p, size_t i, float v) {
    if (B16) ((__hip_bfloat16*)p)[i] = __float2bfloat16(v);
    else     ((float*)p)[i] = v;
}
template<bool B16>
static __device__ __forceinline__ float4 ld4(const void* p, size_t i4) {
    if (B16) {
        uint2 u = ((const uint2*)p)[i4];
        return make_float4(__uint_as_float(u.x << 16), __uint_as_float(u.x & 0xffff0000u),
                           __uint_as_float(u.y << 16), __uint_as_float(u.y & 0xffff0000u));
    } else {
        return ((const float4*)p)[i4];
    }
}
template<bool B16>
static __device__ __forceinline__ void st4(void* p, size_t i4, float4 v) {
    if (B16) {
        stf<true>(p, 4*i4 + 0, v.x); stf<true>(p, 4*i4 + 1, v.y);
        stf<true>(p, 4*i4 + 2, v.z); stf<true>(p, 4*i4 + 3, v.w);
    } else {
        ((float4*)p)[i4] = v;
    }
}
static __device__ __forceinline__ unsigned short f2bf_bits(float x) {
    __hip_bfloat16 b = __float2bfloat16(x);
    return *reinterpret_cast<unsigned short*>(&b);
}
static __device__ __forceinline__ uint32_t pack_bf2(float lo, float hi) {
    return (uint32_t)f2bf_bits(lo) | ((uint32_t)f2bf_bits(hi) << 16);
}
static __device__ __forceinline__ short bfs(float x) {
    unsigned short u = f2bf_bits(x);
    return *reinterpret_cast<short*>(&u);
}
// runtime-dtype vector load/store (isb: 1 = tensors bf16, 0 = f32)
static __device__ __forceinline__ float4 ld4rt(const void* p, size_t i4, int isb) {
    if (isb) {
        uint2 u = ((const uint2*)p)[i4];
        return make_float4(__uint_as_float(u.x << 16), __uint_as_float(u.x & 0xffff0000u),
                           __uint_as_float(u.y << 16), __uint_as_float(u.y & 0xffff0000u));
    }
    return ((const float4*)p)[i4];
}
static __device__ __forceinline__ void st4rt(void* p, size_t i4, float4 v, int isb) {
    if (isb) {
        ((uint2*)p)[i4] = make_uint2(pack_bf2(v.x, v.y), pack_bf2(v.z, v.w));
    } else {
        ((float4*)p)[i4] = v;
    }
}

static __device__ __forceinline__ f32x4 mfma32(bf16x8 a, bf16x8 b, f32x4 c) {
    return __builtin_amdgcn_mfma_f32_16x16x32_bf16(a, b, c, 0, 0, 0);
}
static __device__ __forceinline__ f32x4 mfma16(bf16x4 a, bf16x4 b, f32x4 c) {
#if defined(__has_builtin)
#if __has_builtin(__builtin_amdgcn_mfma_f32_16x16x16bf16_1k)
    return __builtin_amdgcn_mfma_f32_16x16x16bf16_1k(a, b, c, 0, 0, 0);
#define MFMA16_DONE 1
#endif
#endif
#ifndef MFMA16_DONE
    asm volatile("v_mfma_f32_16x16x16_bf16 %0, %1, %2, %0\n\ts_nop 7\n\ts_nop 7"
                 : "+v"(c) : "v"(a), "v"(b));
    return c;
#endif
}

// ---- dtype sniff: P(wrong) ~ 0.48^128 ----
__global__ void sniff_kernel(const uint32_t* __restrict__ w, float* __restrict__ ws) {
    int bad = 0;
    for (int i = 0; i < 128; ++i) {
        uint32_t d = w[i];
        float a = __uint_as_float(d << 16);
        float b = __uint_as_float(d & 0xffff0000u);
        if (!(fabsf(a) <= 0.1f)) bad++;
        if (!(fabsf(b) <= 0.1f)) bad++;
    }
    ((int*)ws)[O_FLAG] = (bad == 0) ? 1 : 0;
}

// ---- weights -> fp32 in ws; W2/Wn2/WC1T transposed ----
__global__ void prep_kernel(
    const void* We1, const void* be1, const void* We2, const void* be2,
    const void* Wn1, const void* bn1, const void* Wn2, const void* bn2,
    const void* Wc1, const void* bc1, const void* Wc2, const void* bc2,
    float* __restrict__ wf)
{
    const int isb = ((const int*)wf)[O_FLAG];
    int tid = blockIdx.x * blockDim.x + threadIdx.x;
    int stride = gridDim.x * blockDim.x;
#define LD(src, i) (isb ? bf2f(((const __hip_bfloat16*)(src))[i]) : ((const float*)(src))[i])
#define CP(dst, src, n)  for (int i = tid; i < (n); i += stride) wf[(dst) + i] = LD(src, i);
#define CPT(dst, src)    for (int i = tid; i < 4096; i += stride) \
        wf[(dst) + (i & 63) * 64 + (i >> 6)] = LD(src, i);
    CP(O_W1,  We1, 129*64)  CP(O_B1,  be1, 64)
    CPT(O_W2,  We2)         CP(O_B2,  be2, 64)
    CP(O_WC1, Wc1, 64*64)   CP(O_BC1, bc1, 64)
    CPT(O_WC1T, Wc1)
    CP(O_WC2, Wc2, 64)      CP(O_BC2, bc2, 1)
    CP(O_WN1, Wn1, 128*64)  CP(O_BN1, bn1, 64)
    CPT(O_WN2, Wn2)         CP(O_BN2, bn2, 64)
#undef CP
#undef CPT
#undef LD
}

// ---- R11 (HW-verified): MFMA pre_edge — Y^T = We1^T @ h^T (+b1 on row half).
__global__ __launch_bounds__(256, 3) void pre_edge_kernel(
    const void* __restrict__ h, float* __restrict__ ws)
{
    const int isb = ((const int*)ws)[O_FLAG];
    __shared__ bf16x8 s_wh[16][64];                // We1^T frags [2t+s][lane]
    __shared__ bf16x8 s_wl[16][64];
    __shared__ __align__(16) float s_b1[64];

    const int tid = threadIdx.x;
    for (int f = tid; f < 1024; f += 256) {
        int frag = f >> 6, l = f & 63;
        int t = frag >> 1, s = frag & 1, e2 = l & 15, g2 = l >> 4;
        const float* p = ws + O_W1 + (size_t)((t >= 4 ? 64 : 0) + 32*s + 8*g2) * 64
                         + 16*(t & 3) + e2;
        bf16x8 rh, rl;
        #pragma unroll
        for (int j = 0; j < 8; ++j) {
            float w = p[j * 64];
            unsigned short hb = f2bf_bits(w);
            rh[j] = (short)hb;
            rl[j] = bfs(w - __uint_as_float((uint32_t)hb << 16));
        }
        s_wh[frag][l] = rh; s_wl[frag][l] = rl;
    }
    for (int i = tid; i < 64; i += 256) s_b1[i] = ws[O_B1 + i];
    __syncthreads();

    const int lane = tid & 63, e = lane & 15, g = lane >> 4;
    const int c = blockIdx.x * 4 + (tid >> 6);
    if (c >= NN / 16) return;
    asm volatile("" ::: "memory");                 // keep LDS reads below (R8 lesson)
    const int n = c * 16 + e;

    bf16x8 bhi[2], blo[2];
    #pragma unroll
    for (int s = 0; s < 2; ++s) {
        float4 a0 = ld4rt(h, (size_t)n * 16 + 8*s + 2*g, isb);
        float4 a1 = ld4rt(h, (size_t)n * 16 + 8*s + 2*g + 1, isb);
        float a[8] = {a0.x, a0.y, a0.z, a0.w, a1.x, a1.y, a1.z, a1.w};
        bf16x8 h8, l8;
        #pragma unroll
        for (int j = 0; j < 8; ++j) {
            unsigned short hb = f2bf_bits(a[j]);
            h8[j] = (short)hb;
            l8[j] = bfs(a[j] - __uint_as_float((uint32_t)hb << 16));
        }
        bhi[s] = h8; blo[s] = l8;
    }

    #pragma unroll
    for (int t = 0; t < 8; ++t) {
        f32x4 d;
        if (t < 4) d = *(const f32x4*)&s_b1[16*t + 4*g];
        else       d = (f32x4){0.0f, 0.0f, 0.0f, 0.0f};
        #pragma unroll
        for (int s = 0; s < 2; ++s) {
            bf16x8 wh = s_wh[2*t + s][lane];
            bf16x8 wl = s_wl[2*t + s][lane];
            d = mfma32(wh, bhi[s], d);
            d = mfma32(wh, blo[s], d);
            d = mfma32(wl, bhi[s], d);
        }
        *(float4*)(ws + O_Y + (size_t)n * 128 + 16*t + 4*g) =
            make_float4(d[0], d[1], d[2], d[3]);
    }
}

// ---- edge MLP scalar core (atomic-fallback only) ----
template<bool B16>
static __device__ __forceinline__ void edge_mlp(
    const void* __restrict__ coord, const float* __restrict__ wf,
    int row, int col,
    float4 efbuf[16], float& gate, float& cdx, float& cdy, float& cdz)
{
    cdx = ldf<B16>(coord, 3*row + 0) - ldf<B16>(coord, 3*col + 0);
    cdy = ldf<B16>(coord, 3*row + 1) - ldf<B16>(coord, 3*col + 1);
    cdz = ldf<B16>(coord, 3*row + 2) - ldf<B16>(coord, 3*col + 2);
    float radial = cdx*cdx + cdy*cdy + cdz*cdz;

    const float4* yrv = (const float4*)(wf + O_Y + (size_t)row * 128);
    const float4* ycv = (const float4*)(wf + O_Y + (size_t)col * 128 + 64);

    float acc[64];
    #pragma unroll
    for (int q = 0; q < 16; ++q) {
        float4 a = yrv[q];
        float4 b = ycv[q];
        const float* wr = wf + O_W1 + 128 * 64 + q * 4;
        acc[4*q+0] = fmaxf(fmaf(radial, wr[0], a.x + b.x), 0.0f);
        acc[4*q+1] = fmaxf(fmaf(radial, wr[1], a.y + b.y), 0.0f);
        acc[4*q+2] = fmaxf(fmaf(radial, wr[2], a.z + b.z), 0.0f);
        acc[4*q+3] = fmaxf(fmaf(radial, wr[3], a.w + b.w), 0.0f);
    }

    #pragma unroll
    for (int j0 = 0; j0 < 16; ++j0) {
        float c[4];
        #pragma unroll
        for (int u = 0; u < 4; ++u) {
            int j = j0 * 4 + u;
            float t = wf[O_B2 + j];
            const float* w2t = wf + O_W2 + j * 64;
            #pragma unroll
            for (int k = 0; k < 64; ++k) t = fmaf(acc[k], w2t[k], t);
            c[u] = fmaxf(t, 0.0f);
        }
        efbuf[j0] = make_float4(c[0], c[1], c[2], c[3]);
    }

    float hid[64];
    #pragma unroll
    for (int j = 0; j < 64; ++j) hid[j] = wf[O_BC1 + j];
    #pragma unroll
    for (int j0 = 0; j0 < 16; ++j0) {
        float4 ef4 = efbuf[j0];
        const float* w0 = wf + O_WC1 + (j0 * 4 + 0) * 64;
        const float* w1 = wf + O_WC1 + (j0 * 4 + 1) * 64;
        const float* w2 = wf + O_WC1 + (j0 * 4 + 2) * 64;
        const float* w3 = wf + O_WC1 + (j0 * 4 + 3) * 64;
        #pragma unroll
        for (int jj = 0; jj < 64; ++jj) hid[jj] = fmaf(ef4.x, w0[jj], hid[jj]);
        #pragma unroll
        for (int jj = 0; jj < 64; ++jj) hid[jj] = fmaf(ef4.y, w1[jj], hid[jj]);
        #pragma unroll
        for (int jj = 0; jj < 64; ++jj) hid[jj] = fmaf(ef4.z, w2[jj], hid[jj]);
        #pragma unroll
        for (int jj = 0; jj < 64; ++jj) hid[jj] = fmaf(ef4.w, w3[jj], hid[jj]);
    }

    float g0 = wf[O_BC2], g1 = 0.0f, g2 = 0.0f, g3 = 0.0f;
    #pragma unroll
    for (int j = 0; j < 64; j += 4) {
        g0 = fmaf(fmaxf(hid[j + 0], 0.0f), wf[O_WC2 + j + 0], g0);
        g1 = fmaf(fmaxf(hid[j + 1], 0.0f), wf[O_WC2 + j + 1], g1);
        g2 = fmaf(fmaxf(hid[j + 2], 0.0f), wf[O_WC2 + j + 2], g2);
        g3 = fmaf(fmaxf(hid[j + 3], 0.0f), wf[O_WC2 + j + 3], g3);
    }
    gate = (g0 + g1) + (g2 + g3);
}

// ============ CSR path ============
__global__ __launch_bounds__(256) void count_kernel(
    const int* __restrict__ ei, float* __restrict__ ws)
{
    int e = blockIdx.x * 256 + threadIdx.x;
    if (e >= NE) return;
    atomicAdd((int*)ws + N_CNT + ei[e], 1);
}

// R12 (HW-verified): 4 elements/thread, 13 iterations.
__global__ __launch_bounds__(1024) void scan_kernel(float* __restrict__ ws) {
    int* cnt = (int*)ws + N_CNT;
    int* off = (int*)ws + N_OFF;
    __shared__ int wsum[16];
    __shared__ int carry_s;
    int tid = threadIdx.x, lane = tid & 63, wid = tid >> 6;
    if (tid == 0) carry_s = 0;
    __syncthreads();
    for (int base = 0; base < NN; base += 4096) {
        int i0 = base + tid * 4;
        int a0 = (i0 + 0 < NN) ? cnt[i0 + 0] : 0;
        int a1 = (i0 + 1 < NN) ? cnt[i0 + 1] : 0;
        int a2 = (i0 + 2 < NN) ? cnt[i0 + 2] : 0;
        int a3 = (i0 + 3 < NN) ? cnt[i0 + 3] : 0;
        int tsum = ((a0 + a1) + (a2 + a3));
        int v = tsum;
        #pragma unroll
        for (int s = 1; s < 64; s <<= 1) { int t = __shfl_up(v, s, 64); if (lane >= s) v += t; }
        if (lane == 63) wsum[wid] = v;
        __syncthreads();
        if (wid == 0) {
            int w = (lane < 16) ? wsum[lane] : 0;
            #pragma unroll
            for (int s = 1; s < 16; s <<= 1) { int t = __shfl_up(w, s, 64); if (lane >= s) w += t; }
            if (lane < 16) wsum[lane] = w;
        }
        __syncthreads();
        int waveback = (wid > 0) ? wsum[wid - 1] : 0;
        int excl = carry_s + waveback + (v - tsum);
        if (i0 + 0 < NN) { off[i0 + 0] = excl; cnt[i0 + 0] = excl; }
        excl += a0;
        if (i0 + 1 < NN) { off[i0 + 1] = excl; cnt[i0 + 1] = excl; }
        excl += a1;
        if (i0 + 2 < NN) { off[i0 + 2] = excl; cnt[i0 + 2] = excl; }
        excl += a2;
        if (i0 + 3 < NN) { off[i0 + 3] = excl; cnt[i0 + 3] = excl; }
        __syncthreads();
        if (tid == 0) carry_s += wsum[15];
        __syncthreads();
    }
    if (threadIdx.x == 0) off[NN] = carry_s;
}

// store col only (4B) — row is implicit in the node-based edge kernel.
__global__ __launch_bounds__(256) void scatter_kernel(
    const int* __restrict__ ei, float* __restrict__ ws)
{
    int e = blockIdx.x * 256 + threadIdx.x;
    if (e >= NE) return;
    int row = ei[e];
    int col = ei[NE + e];
    int pos = atomicAdd((int*)ws + N_CNT + row, 1);
    ((int*)ws + N_RC)[pos] = col;
}

// ---- R17: node-based MFMA edge kernel with FUSED aggregation.
// R12 verified the chunk-loop fence + scalarization (WRITE 1.4GB -> 14MB,
// 110.9us). R13 change: occupancy 3->6 waves/EU (R12 counters: Occ 34.4% ==
// the (256,3) cap, VALU 43 / MFMA 18 / HBM 12 all unsaturated, VGPR 64,
// LDS 25.5KB x 6 = 153KB fits). Latency + tail-imbalance bound -> more TLP.
#define SPLIT1(H, L, IDX, VAL, WI) { \
    float _v = fmaxf(fmaf(radial, s_w1r[WI], (VAL)), 0.0f); \
    unsigned short _hb = f2bf_bits(_v); \
    H[IDX] = (short)_hb; \
    L[IDX] = bfs(_v - __uint_as_float((uint32_t)_hb << 16)); }
#define SPLIT8(H, L, WOFF, V0,V1,V2,V3,V4,V5,V6,V7) \
    SPLIT1(H,L,0,V0,(WOFF)+0) SPLIT1(H,L,1,V1,(WOFF)+1) \
    SPLIT1(H,L,2,V2,(WOFF)+2) SPLIT1(H,L,3,V3,(WOFF)+3) \
    SPLIT1(H,L,4,V4,(WOFF)+4) SPLIT1(H,L,5,V5,(WOFF)+5) \
    SPLIT1(H,L,6,V6,(WOFF)+6) SPLIT1(H,L,7,V7,(WOFF)+7)
#define PHASEB(D, T) { \
    bf16x8 wh0 = s_wbh[2*(T)+0][lane], wh1 = s_wbh[2*(T)+1][lane]; \
    bf16x8 wl0 = s_wbl[2*(T)+0][lane], wl1 = s_wbl[2*(T)+1][lane]; \
    D = mfma32(wh0, ahi0, D); D = mfma32(wh1, ahi1, D); \
    D = mfma32(wh0, alo0, D); D = mfma32(wh1, alo1, D); \
    D = mfma32(wl0, ahi0, D); D = mfma32(wl1, ahi1, D); }
#define EFBLK(D, BQ, A0,A1,A2,A3) { \
    float _e0 = fmaxf(D[0], 0.0f) * vmask; \
    float _e1 = fmaxf(D[1], 0.0f) * vmask; \
    float _e2 = fmaxf(D[2], 0.0f) * vmask; \
    float _e3 = fmaxf(D[3], 0.0f) * vmask; \
    BQ[0] = (short)f2bf_bits(_e0); BQ[1] = (short)f2bf_bits(_e1); \
    BQ[2] = (short)f2bf_bits(_e2); BQ[3] = (short)f2bf_bits(_e3); \
    A0 += _e0; A1 += _e1; A2 += _e2; A3 += _e3; }
#define PHASEC(D, U) { \
    D = mfma16(s_wc[4*(U)+0][lane], bq0, D); \
    D = mfma16(s_wc[4*(U)+1][lane], bq1, D); \
    D = mfma16(s_wc[4*(U)+2][lane], bq2, D); \
    D = mfma16(s_wc[4*(U)+3][lane], bq3, D); }
#define GATEU(D, U) { \
    gp = fmaf(fmaxf(D[0], 0.0f), s_wc2[16*(U) + 4*g + 0], gp); \
    gp = fmaf(fmaxf(D[1], 0.0f), s_wc2[16*(U) + 4*g + 1], gp); \
    gp = fmaf(fmaxf(D[2], 0.0f), s_wc2[16*(U) + 4*g + 2], gp); \
    gp = fmaf(fmaxf(D[3], 0.0f), s_wc2[16*(U) + 4*g + 3], gp); }
#define RED16(M) \
    ag00 += __shfl_xor(ag00,M,64); ag01 += __shfl_xor(ag01,M,64); \
    ag02 += __shfl_xor(ag02,M,64); ag03 += __shfl_xor(ag03,M,64); \
    ag10 += __shfl_xor(ag10,M,64); ag11 += __shfl_xor(ag11,M,64); \
    ag12 += __shfl_xor(ag12,M,64); ag13 += __shfl_xor(ag13,M,64); \
    ag20 += __shfl_xor(ag20,M,64); ag21 += __shfl_xor(ag21,M,64); \
    ag22 += __shfl_xor(ag22,M,64); ag23 += __shfl_xor(ag23,M,64); \
    ag30 += __shfl_xor(ag30,M,64); ag31 += __shfl_xor(ag31,M,64); \
    ag32 += __shfl_xor(ag32,M,64); ag33 += __shfl_xor(ag33,M,64);

__global__ __launch_bounds__(256, 6) void edge_csr_kernel(
    const void* __restrict__ coord, float* __restrict__ ws)
{
    const int isb = ((const int*)ws)[O_FLAG];

    __shared__ bf16x8 s_wbh[8][64];                // We2^T hi frags [2t+s][lane], 8KB
    __shared__ bf16x8 s_wbl[8][64];                // We2^T lo frags, 8KB
    __shared__ bf16x4 s_wc[16][64];                // Wc1^T frags [4u+t][lane], 8KB
    __shared__ __align__(16) float s_b2[64];
    __shared__ __align__(16) float s_bc1[64];
    __shared__ __align__(16) float s_wc2[64];
    __shared__ float s_w1r[64];
    __shared__ float s_bc2v;

    const int tid = threadIdx.x;
    for (int f = tid; f < 512; f += 256) {         // We2^T hi/lo fill
        int frag = f >> 6, l = f & 63;
        int t = frag >> 1, s = frag & 1, e2 = l & 15, g2 = l >> 4;
        const float* p = ws + O_W2 + (16*t + e2)*64 + 32*s + 8*g2;
        bf16x8 rh, rl;
        #pragma unroll
        for (int j = 0; j < 8; ++j) {
            float w = p[j];
            unsigned short hb = f2bf_bits(w);
            rh[j] = (short)hb;
            float hf = __uint_as_float((uint32_t)hb << 16);
            rl[j] = bfs(w - hf);
        }
        s_wbh[frag][l] = rh;
        s_wbl[frag][l] = rl;
    }
    for (int f = tid; f < 1024; f += 256) {        // Wc1^T fill (hi only)
        int frag = f >> 6, l = f & 63;
        int u = frag >> 2, t = frag & 3, e2 = l & 15, g2 = l >> 4;
        const float* p = ws + O_WC1T + (16*u + e2)*64 + 16*t + 4*g2;
        bf16x4 r;
        #pragma unroll
        for (int j = 0; j < 4; ++j) r[j] = bfs(p[j]);
        s_wc[frag][l] = r;
    }
    for (int i = tid; i < 64; i += 256) {
        s_b2[i]  = ws[O_B2 + i];
        s_bc1[i] = ws[O_BC1 + i];
        s_wc2[i] = ws[O_WC2 + i];
        s_w1r[i] = ws[O_W1 + 128*64 + i];          // radial row of We1
    }
    if (tid == 0) s_bc2v = ws[O_BC2];
    __syncthreads();

    const int lane = threadIdx.x & 63;
    const int e = lane & 15, g = lane >> 4;
    const int wid = blockIdx.x * 4 + (int)(threadIdx.x >> 6);
    const int nw = 6144;                           // grid is exactly 1536 blocks
    const int* off = (const int*)ws + N_OFF;
    const int* colA = (const int*)ws + N_RC;
    const float* cf = (const float*)coord;
    const __hip_bfloat16* cbh = (const __hip_bfloat16*)coord;

    for (int n = wid; n < NN; n += nw) {
        const int s0 = off[n], s1 = off[n + 1];

        // node (row) coords — wave-uniform
        float crx, cry, crz;
        if (isb) {
            crx = bf2f(cbh[3*n+0]); cry = bf2f(cbh[3*n+1]); crz = bf2f(cbh[3*n+2]);
        } else {
            crx = cf[3*n+0]; cry = cf[3*n+1]; crz = cf[3*n+2];
        }
        // row-half Y (k = 32s + 8g + j) — uniform across e-lanes; SCALARIZED
        float y00, y01, y02, y03, y04, y05, y06, y07;
        float y10, y11, y12, y13, y14, y15, y16, y17;
        {
            const float4* yr4 = (const float4*)(ws + O_Y + (size_t)n * 128 + 8*g);
            float4 ra = yr4[0], rb = yr4[1];
            y00=ra.x; y01=ra.y; y02=ra.z; y03=ra.w;
            y04=rb.x; y05=rb.y; y06=rb.z; y07=rb.w;
        }
        {
            const float4* yr4 = (const float4*)(ws + O_Y + (size_t)n * 128 + 32 + 8*g);
            float4 ra = yr4[0], rb = yr4[1];
            y10=ra.x; y11=ra.y; y12=ra.z; y13=ra.w;
            y14=rb.x; y15=rb.y; y16=rb.z; y17=rb.w;
        }

        // SCALARIZED accumulators (rule #20 hard-proofing)
        float ag00=0.f, ag01=0.f, ag02=0.f, ag03=0.f;
        float ag10=0.f, ag11=0.f, ag12=0.f, ag13=0.f;
        float ag20=0.f, ag21=0.f, ag22=0.f, ag23=0.f;
        float ag30=0.f, ag31=0.f, ag32=0.f, ag33=0.f;
        float tx = 0.0f, ty = 0.0f, tz = 0.0f;

        for (int base = s0; base < s1; base += 16) {
            // anti-LICM fence INSIDE the weight-consuming loop (R12-proven
            // placement; a node-level fence lets LICM hoist the LDS weight
            // reads out of this loop -> spill -> GB-scale scratch traffic).
            asm volatile("" ::: "memory");

            const int cnt = s1 - base;             // >= 1 here
            const bool valid = e < cnt;
            const int col = colA[base + (valid ? e : 0)];

            float ccx, ccy, ccz;
            if (isb) {
                ccx = bf2f(cbh[3*col+0]); ccy = bf2f(cbh[3*col+1]); ccz = bf2f(cbh[3*col+2]);
            } else {
                ccx = cf[3*col+0]; ccy = cf[3*col+1]; ccz = cf[3*col+2];
            }
            float cdx = crx - ccx, cdy = cry - ccy, cdz = crz - ccz;
            float radial = cdx*cdx + cdy*cdy + cdz*cdz;

            // acc (k = 32s + 8g + j) in fp32, split hi/lo bf16 — SCALARIZED
            const float* Yc = ws + O_Y + (size_t)col * 128 + 64;
            bf16x8 ahi0, alo0, ahi1, alo1;
            {
                const float4* yc4 = (const float4*)(Yc + 8*g);
                float4 ca = yc4[0], cb4 = yc4[1];
                SPLIT8(ahi0, alo0, 8*g,
                       y00+ca.x, y01+ca.y, y02+ca.z, y03+ca.w,
                       y04+cb4.x, y05+cb4.y, y06+cb4.z, y07+cb4.w)
            }
            {
                const float4* yc4 = (const float4*)(Yc + 32 + 8*g);
                float4 ca = yc4[0], cb4 = yc4[1];
                SPLIT8(ahi1, alo1, 32 + 8*g,
                       y10+ca.x, y11+ca.y, y12+ca.z, y13+ca.w,
                       y14+cb4.x, y15+cb4.y, y16+cb4.z, y17+cb4.w)
            }

            // phase B: D1[ef][edge], C-init = b2; 3-product hi/lo
            f32x4 d10 = *(const f32x4*)&s_b2[ 0 + 4*g];
            f32x4 d11 = *(const f32x4*)&s_b2[16 + 4*g];
            f32x4 d12 = *(const f32x4*)&s_b2[32 + 4*g];
            f32x4 d13 = *(const f32x4*)&s_b2[48 + 4*g];
            PHASEB(d10, 0) PHASEB(d11, 1) PHASEB(d12, 2) PHASEB(d13, 3)

            // relu (fp32) + validity mask; bq = bf16(ef) for the gate path
            const float vmask = valid ? 1.0f : 0.0f;
            bf16x4 bq0, bq1, bq2, bq3;
            EFBLK(d10, bq0, ag00, ag01, ag02, ag03)
            EFBLK(d11, bq1, ag10, ag11, ag12, ag13)
            EFBLK(d12, bq2, ag20, ag21, ag22, ag23)
            EFBLK(d13, bq3, ag30, ag31, ag32, ag33)

            // phase C: D2[hid][edge] = Wc1^T @ ef^T, C-init = bc1
            f32x4 d20 = *(const f32x4*)&s_bc1[ 0 + 4*g];
            f32x4 d21 = *(const f32x4*)&s_bc1[16 + 4*g];
            f32x4 d22 = *(const f32x4*)&s_bc1[32 + 4*g];
            f32x4 d23 = *(const f32x4*)&s_bc1[48 + 4*g];
            PHASEC(d20, 0) PHASEC(d21, 1) PHASEC(d22, 2) PHASEC(d23, 3)

            // gate = bc2 + sum_h relu(hid[h]) * Wc2[h]; reduce over 4 g-groups
            float gp = 0.0f;
            GATEU(d20, 0) GATEU(d21, 1) GATEU(d22, 2) GATEU(d23, 3)
            gp += __shfl_xor(gp, 16, 64);
            gp += __shfl_xor(gp, 32, 64);
            float gate = gp + s_bc2v;

            if (valid && g == 0) {
                tx += fminf(fmaxf(cdx * gate, -100.0f), 100.0f);
                ty += fminf(fmaxf(cdy * gate, -100.0f), 100.0f);
                tz += fminf(fmaxf(cdz * gate, -100.0f), 100.0f);
            }
        }

        // cross-edge reduce of agg (over e-lanes, within each g-group)
        RED16(1) RED16(2) RED16(4) RED16(8)

        // write agg row: lane (e=t, g) stores features 16t+4g+{0..3}
        float* aggw = ws + N_AGGH + (size_t)n * 64;
        if (e == 0)      *(float4*)(aggw + 0  + 4*g) = make_float4(ag00, ag01, ag02, ag03);
        else if (e == 1) *(float4*)(aggw + 16 + 4*g) = make_float4(ag10, ag11, ag12, ag13);
        else if (e == 2) *(float4*)(aggw + 32 + 4*g) = make_float4(ag20, ag21, ag22, ag23);
        else if (e == 3) *(float4*)(aggw + 48 + 4*g) = make_float4(ag30, ag31, ag32, ag33);

        // cross-edge reduce of trans (g==0 lanes hold partials)
        tx += __shfl_xor(tx, 1, 64); ty += __shfl_xor(ty, 1, 64); tz += __shfl_xor(tz, 1, 64);
        tx += __shfl_xor(tx, 2, 64); ty += __shfl_xor(ty, 2, 64); tz += __shfl_xor(tz, 2, 64);
        tx += __shfl_xor(tx, 4, 64); ty += __shfl_xor(ty, 4, 64); tz += __shfl_xor(tz, 4, 64);
        tx += __shfl_xor(tx, 8, 64); ty += __shfl_xor(ty, 8, 64); tz += __shfl_xor(tz, 8, 64);
        if (lane == 0) {
            ws[N_SUMT + 3*(size_t)n + 0] = tx;
            ws[N_SUMT + 3*(size_t)n + 1] = ty;
            ws[N_SUMT + 3*(size_t)n + 2] = tz;
        }
    }
}
#undef SPLIT1
#undef SPLIT8
#undef PHASEB
#undef EFBLK
#undef PHASEC
#undef GATEU
#undef RED16

// ---- scalar node core (atomic fallback only) ----
template<bool B16>
static __device__ __forceinline__ void node_core(
    const void* __restrict__ h, const void* __restrict__ coord,
    const void* __restrict__ vel, const float* __restrict__ ws,
    const float* __restrict__ agg, const float* __restrict__ sumt, float cntf,
    void* __restrict__ out, int n)
{
    float inv = (cntf > 0.0f) ? (1.0f / fmaxf(cntf, 1.0f)) : 0.0f;
    #pragma unroll
    for (int i = 0; i < 3; ++i) {
        float aggc = sumt[3*n + i] * inv;
        float v = ldf<B16>(vel, 3*n + i) + aggc * 0.125f;
        float cn = ldf<B16>(coord, 3*n + i) + v * 0.125f;
        stf<B16>(out, OUT_COORD + 3*n + i, cn);
        stf<B16>(out, OUT_V + 3*n + i, v);
    }

    float acc[64];
    #pragma unroll
    for (int j = 0; j < 64; ++j) acc[j] = ws[O_BN1 + j];

    #pragma unroll 4
    for (int q = 0; q < 16; ++q) {
        float4 a = ld4<B16>(h, (size_t)n * 16 + q);
        const float* w = ws + O_WN1 + (q * 4) * 64;
        #pragma unroll
        for (int j = 0; j < 64; ++j) acc[j] = fmaf(a.x, w[j], acc[j]);
        #pragma unroll
        for (int j = 0; j < 64; ++j) acc[j] = fmaf(a.y, w[64 + j], acc[j]);
        #pragma unroll
        for (int j = 0; j < 64; ++j) acc[j] = fmaf(a.z, w[128 + j], acc[j]);
        #pragma unroll
        for (int j = 0; j < 64; ++j) acc[j] = fmaf(a.w, w[192 + j], acc[j]);
    }
    const float4* agv = (const float4*)(agg + (size_t)n * 64);
    #pragma unroll 4
    for (int q = 0; q < 16; ++q) {
        float4 a = agv[q];
        const float* w = ws + O_WN1 + (64 + q * 4) * 64;
        #pragma unroll
        for (int j = 0; j < 64; ++j) acc[j] = fmaf(a.x, w[j], acc[j]);
        #pragma unroll
        for (int j = 0; j < 64; ++j) acc[j] = fmaf(a.y, w[64 + j], acc[j]);
        #pragma unroll
        for (int j = 0; j < 64; ++j) acc[j] = fmaf(a.z, w[128 + j], acc[j]);
        #pragma unroll
        for (int j = 0; j < 64; ++j) acc[j] = fmaf(a.w, w[192 + j], acc[j]);
    }
    #pragma unroll
    for (int j = 0; j < 64; ++j) acc[j] = fmaxf(acc[j], 0.0f);

    float4 ob[16];
    #pragma unroll
    for (int j0 = 0; j0 < 16; ++j0) {
        float4 hres = ld4<B16>(h, (size_t)n * 16 + j0);
        float c[4];
        #pragma unroll
        for (int u = 0; u < 4; ++u) {
            int j = j0 * 4 + u;
            float t = ws[O_BN2 + j];
            const float* w = ws + O_WN2 + j * 64;
            #pragma unroll
            for (int k = 0; k < 64; ++k) t = fmaf(acc[k], w[k], t);
            c[u] = t;
        }
        ob[j0] = make_float4(hres.x + c[0], hres.y + c[1], hres.z + c[2], hres.w + c[3]);
    }
    #pragma unroll
    for (int j0 = 0; j0 < 16; ++j0) st4<B16>(out, (size_t)n * 16 + j0, ob[j0]);
}

// ---- R11 (HW-verified): MFMA node kernel (CSR path, both dtypes).
__global__ __launch_bounds__(256, 3) void node_kernel_csr(
    const void* __restrict__ h, const void* __restrict__ coord,
    const void* __restrict__ vel, const float* __restrict__ ws,
    void* __restrict__ out)
{
    const int isb = ((const int*)ws)[O_FLAG];

    __shared__ bf16x8 s_w1h[16][64];               // Wn1^T frags [4t+s][lane], 16KB
    __shared__ bf16x8 s_w1l[16][64];               // 16KB
    __shared__ bf16x4 s_w2h[16][64];               // Wn2^T frags [4u+t][lane], 8KB
    __shared__ bf16x4 s_w2l[16][64];               // 8KB
    __shared__ __align__(16) float s_bn1[64];
    __shared__ __align__(16) float s_bn2[64];

    const int tid = threadIdx.x;
    for (int f = tid; f < 1024; f += 256) {        // Wn1^T hi/lo fill
        int frag = f >> 6, l = f & 63;
        int t = frag >> 2, s = frag & 3, e2 = l & 15, g2 = l >> 4;
        const float* p = ws + O_WN1 + (size_t)(32*s + 8*g2) * 64 + 16*t + e2;
        bf16x8 rh, rl;
        #pragma unroll
        for (int j = 0; j < 8; ++j) {
            float w = p[j * 64];
            unsigned short hb = f2bf_bits(w);
            rh[j] = (short)hb;
            rl[j] = bfs(w - __uint_as_float((uint32_t)hb << 16));
        }
        s_w1h[frag][l] = rh; s_w1l[frag][l] = rl;
    }
    for (int f = tid; f < 1024; f += 256) {        // Wn2^T hi/lo fill
        int frag = f >> 6, l = f & 63;
        int u = frag >> 2, t = frag & 3, e2 = l & 15, g2 = l >> 4;
        const float* p = ws + O_WN2 + (16*u + e2) * 64 + 16*t + 4*g2;
        bf16x4 rh, rl;
        #pragma unroll
        for (int j = 0; j < 4; ++j) {
            float w = p[j];
            unsigned short hb = f2bf_bits(w);
            rh[j] = (short)hb;
            rl[j] = bfs(w - __uint_as_float((uint32_t)hb << 16));
        }
        s_w2h[frag][l] = rh; s_w2l[frag][l] = rl;
    }
    for (int i = tid; i < 64; i += 256) { s_bn1[i] = ws[O_BN1 + i]; s_bn2[i] = ws[O_BN2 + i]; }
    __syncthreads();

    const int lane = tid & 63, e = lane & 15, g = lane >> 4;
    const int c = blockIdx.x * 4 + (tid >> 6);
    if (c >= NN / 16) return;
    asm volatile("" ::: "memory");                 // anti-LICM
    const int n = c * 16 + e;

    // coord / vel epilogue on g==0 lanes
    if (g == 0) {
        const int* off = (const int*)ws + N_OFF;
        float cntf = (float)(off[n + 1] - off[n]);
        float inv = (cntf > 0.0f) ? (1.0f / fmaxf(cntf, 1.0f)) : 0.0f;
        #pragma unroll
        for (int i = 0; i < 3; ++i) {
            float aggc = ws[N_SUMT + 3*n + i] * inv;
            float vv, cc;
            if (isb) {
                vv = bf2f(((const __hip_bfloat16*)vel)[3*n + i]);
                cc = bf2f(((const __hip_bfloat16*)coord)[3*n + i]);
            } else {
                vv = ((const float*)vel)[3*n + i];
                cc = ((const float*)coord)[3*n + i];
            }
            float v = vv + aggc * 0.125f;
            float cn = cc + v * 0.125f;
            if (isb) {
                ((__hip_bfloat16*)out)[OUT_COORD + 3*n + i] = __float2bfloat16(cn);
                ((__hip_bfloat16*)out)[OUT_V + 3*n + i] = __float2bfloat16(v);
            } else {
                ((float*)out)[OUT_COORD + 3*n + i] = cn;
                ((float*)out)[OUT_V + 3*n + i] = v;
            }
        }
    }

    // B-op: K=128 = h[0:64] ++ agg[0:64], hi/lo split (k = 32s + 8g + j)
    bf16x8 bhi[4], blo[4];
    #pragma unroll
    for (int s = 0; s < 4; ++s) {
        float a[8];
        if (s < 2) {
            float4 a0 = ld4rt(h, (size_t)n * 16 + 8*s + 2*g, isb);
            float4 a1 = ld4rt(h, (size_t)n * 16 + 8*s + 2*g + 1, isb);
            a[0]=a0.x; a[1]=a0.y; a[2]=a0.z; a[3]=a0.w;
            a[4]=a1.x; a[5]=a1.y; a[6]=a1.z; a[7]=a1.w;
        } else {
            const float4* ag = (const float4*)(ws + N_AGGH + (size_t)n * 64);
            float4 a0 = ag[8*(s-2) + 2*g];
            float4 a1 = ag[8*(s-2) + 2*g + 1];
            a[0]=a0.x; a[1]=a0.y; a[2]=a0.z; a[3]=a0.w;
            a[4]=a1.x; a[5]=a1.y; a[6]=a1.z; a[7]=a1.w;
        }
        bf16x8 h8, l8;
        #pragma unroll
        for (int j = 0; j < 8; ++j) {
            unsigned short hb = f2bf_bits(a[j]);
            h8[j] = (short)hb;
            l8[j] = bfs(a[j] - __uint_as_float((uint32_t)hb << 16));
        }
        bhi[s] = h8; blo[s] = l8;
    }

    // N1 (3-product hi/lo)
    f32x4 d1[4];
    #pragma unroll
    for (int t = 0; t < 4; ++t) d1[t] = *(const f32x4*)&s_bn1[16*t + 4*g];
    #pragma unroll
    for (int t = 0; t < 4; ++t) {
        #pragma unroll
        for (int s = 0; s < 4; ++s) {
            bf16x8 wh = s_w1h[4*t + s][lane];
            bf16x8 wl = s_w1l[4*t + s][lane];
            d1[t] = mfma32(wh, bhi[s], d1[t]);
            d1[t] = mfma32(wh, blo[s], d1[t]);
            d1[t] = mfma32(wl, bhi[s], d1[t]);
        }
    }

    // relu -> hi/lo fragments (features 16t+4g+{0..3})
    bf16x4 rhi[4], rlo[4];
    #pragma unroll
    for (int t = 0; t < 4; ++t) {
        #pragma unroll
        for (int j = 0; j < 4; ++j) {
            float v = fmaxf(d1[t][j], 0.0f);
            unsigned short hb = f2bf_bits(v);
            rhi[t][j] = (short)hb;
            rlo[t][j] = bfs(v - __uint_as_float((uint32_t)hb << 16));
        }
    }

    // N2 (3-product)
    f32x4 d2[4];
    #pragma unroll
    for (int u = 0; u < 4; ++u) d2[u] = *(const f32x4*)&s_bn2[16*u + 4*g];
    #pragma unroll
    for (int u = 0; u < 4; ++u) {
        #pragma unroll
        for (int t = 0; t < 4; ++t) {
            bf16x4 wh = s_w2h[4*u + t][lane];
            bf16x4 wl = s_w2l[4*u + t][lane];
            d2[u] = mfma16(wh, rhi[t], d2[u]);
            d2[u] = mfma16(wh, rlo[t], d2[u]);
            d2[u] = mfma16(wl, rhi[t], d2[u]);
        }
    }

    // residual + store (features 16u+4g+{0..3} -> float4 at h[n][16u+4g])
    #pragma unroll
    for (int u = 0; u < 4; ++u) {
        float4 hres = ld4rt(h, (size_t)n * 16 + 4*u + g, isb);
        float4 o = make_float4(hres.x + d2[u][0], hres.y + d2[u][1],
                               hres.z + d2[u][2], hres.w + d2[u][3]);
        st4rt(out, (size_t)n * 16 + 4*u + g, o, isb);
    }
}

// ============ atomic fallback (small ws) ============
template<bool B16>
static __device__ __forceinline__ void edge_atomic_core(
    const void* __restrict__ coord, const int* __restrict__ ei,
    float* __restrict__ ws, int e)
{
    int row = ei[e];
    int col = ei[NE + e];
    float gate, cdx, cdy, cdz;
    float4 efbuf[16];
    edge_mlp<B16>(coord, ws, row, col, efbuf, gate, cdx, cdy, cdz);

    float* ah = ws + F_AGGH + (size_t)row * 64;
    #pragma unroll
    for (int q = 0; q < 16; ++q) {
        unsafeAtomicAdd(&ah[4*q + 0], efbuf[q].x);
        unsafeAtomicAdd(&ah[4*q + 1], efbuf[q].y);
        unsafeAtomicAdd(&ah[4*q + 2], efbuf[q].z);
        unsafeAtomicAdd(&ah[4*q + 3], efbuf[q].w);
    }
    unsafeAtomicAdd(&ws[F_SUMT + 3*row + 0], fminf(fmaxf(cdx * gate, -100.0f), 100.0f));
    unsafeAtomicAdd(&ws[F_SUMT + 3*row + 1], fminf(fmaxf(cdy * gate, -100.0f), 100.0f));
    unsafeAtomicAdd(&ws[F_SUMT + 3*row + 2], fminf(fmaxf(cdz * gate, -100.0f), 100.0f));
    unsafeAtomicAdd(&ws[F_CNT + row], 1.0f);
}

__global__ __launch_bounds__(256, 2) void edge_atomic_kernel(
    const void* __restrict__ coord, const int* __restrict__ ei,
    float* __restrict__ ws)
{
    int e = blockIdx.x * 256 + threadIdx.x;
    if (e >= NE) return;
    if (((const int*)ws)[O_FLAG]) edge_atomic_core<true>(coord, ei, ws, e);
    else                          edge_atomic_core<false>(coord, ei, ws, e);
}

__global__ __launch_bounds__(256, 2) void node_kernel_atomic(
    const void* __restrict__ h, const void* __restrict__ coord,
    const void* __restrict__ vel, const float* __restrict__ ws,
    void* __restrict__ out)
{
    int n = blockIdx.x * 256 + threadIdx.x;
    if (n >= NN) return;
    float cntf = ws[F_CNT + n];
    if (((const int*)ws)[O_FLAG])
        node_core<true>(h, coord, vel, ws, ws + F_AGGH, ws + F_SUMT, cntf, out, n);
    else
        node_core<false>(h, coord, vel, ws, ws + F_AGGH, ws + F_SUMT, cntf, out, n);
}

extern "C" void kernel_launch(void* const* d_in, const int* in_sizes, int n_in,
                              void* d_out, int out_size, void* d_ws, size_t ws_size,
                              hipStream_t stream) {
    const void* h     = d_in[0];
    const void* coord = d_in[1];
    const void* vel   = d_in[2];
    const int* eidx = (const int*)d_in[4];
    float* ws = (float*)d_ws;

    sniff_kernel<<<1, 1, 0, stream>>>((const uint32_t*)d_in[5], ws);
    prep_kernel<<<64, 256, 0, stream>>>(d_in[5], d_in[6], d_in[7], d_in[8],
                                        d_in[9], d_in[10], d_in[11], d_in[12],
                                        d_in[13], d_in[14], d_in[15], d_in[16], ws);
    // 3125 16-node chunks, 4 waves/block -> 782 blocks
    pre_edge_kernel<<<782, 256, 0, stream>>>(h, ws);

    const bool big = ws_size >= (size_t)N_TOTAL * sizeof(float);
    if (big) {
        hipMemsetAsync((char*)d_ws + (size_t)N_CNT * 4, 0, (size_t)NN * 4, stream);
        count_kernel<<<(NE + 255) / 256, 256, 0, stream>>>(eidx, ws);
        scan_kernel<<<1, 1024, 0, stream>>>(ws);
        scatter_kernel<<<(NE + 255) / 256, 256, 0, stream>>>(eidx, ws);
        edge_csr_kernel<<<1536, 256, 0, stream>>>(coord, ws);
        node_kernel_csr<<<782, 256, 0, stream>>>(h, coord, vel, ws, d_out);
    } else {
        hipMemsetAsync((char*)d_ws + (size_t)F_AGGH * 4, 0,
                       (size_t)(F_TOTAL - F_AGGH) * 4, stream);
        edge_atomic_kernel<<<(NE + 255) / 256, 256, 0, stream>>>(coord, eidx, ws);
        node_kernel_atomic<<<(NN + 255) / 256, 256, 0, stream>>>(h, coord, vel, ws, d_out);
    }
}

// Round 14
// 354.065 us; speedup vs baseline: 1.2375x; 1.2375x over previous
//
#include <hip/hip_runtime.h>
#include <hip/hip_bf16.h>
#include <stdint.h>

#define NE 800000
#define NN 50000

// ---- weight region (float offsets). O_W2 / O_WN2 / O_WC1T hold TRANSPOSED weights.
#define O_W1   0          // We1  [129*64] row-major
#define O_B1   8256
#define O_W2   8320       // We2^T [64*64]
#define O_B2   12416
#define O_WC1  12480      // Wc1  [64*64] row-major (atomic-fallback scalar path)
#define O_BC1  16576
#define O_WC2  16640
#define O_BC2  16704
#define O_WN1  16768      // Wn1  [128*64] row-major
#define O_BN1  24960
#define O_WN2  25024      // Wn2^T [64*64]
#define O_BN2  29120
#define O_FLAG 29184      // int: 1 = tensors bf16, 0 = f32
#define O_WC1T 29248      // Wc1^T [64*64] (MFMA path)

// ---- per-node layer-1 precompute (fp32):
// Y[n][0:64]=h[n]@We1[0:64] + b1 (b1 folded), Y[n][64:128]=h[n]@We1[64:128]
#define O_Y    33344                    // float [NN*128]
#define Y_END  (O_Y + NN*128)

// ---- CSR layout. N_RC holds col-only (int[NE]); ef16/tr regions unused
// (agg fused into edge kernel) but kept in the layout for ws-size gating.
#define N_OFF   Y_END                   // int off[NN+1] (padded to 50008)
#define N_CNT   (N_OFF + 50008)         // int count/cursor[NN]
#define N_RC    (N_CNT + NN)            // int col[NE] by position
#define N_AGGH  (N_RC + 2*NE)           // float [NN*64]
#define N_SUMT  (N_AGGH + NN*64)        // float [NN*3]
#define N_EF16  (N_SUMT + NN*3 + 2)     // (unused since R14)
#define N_TR    (N_EF16 + NE*32)        // (unused since R14)
#define N_TOTAL (N_TR + NE*3)           // ~39.5M words ~ 158 MB (ws gate)

// ---- atomic fallback layout ----
#define F_AGGH  Y_END
#define F_SUMT  (F_AGGH + NN*64)
#define F_CNT   (F_SUMT + NN*3)
#define F_TOTAL (F_CNT + NN)

#define OUT_COORD (NN*64)
#define OUT_V     (NN*64 + NN*3)

typedef __attribute__((ext_vector_type(8))) short bf16x8;
typedef __attribute__((ext_vector_type(4))) short bf16x4;
typedef __attribute__((ext_vector_type(4))) float f32x4;

static __device__ __forceinline__ float bf2f(const __hip_bfloat16 x) { return __bfloat162float(x); }

template<bool B16>
static __device__ __forceinline__ float ldf(const void* p, size_t i) {
    if (B16) return __bfloat162float(((const __hip_bfloat16*)p)[i]);
    else     return ((const float*)p)[i];
}
template<bool B16>
static __device__ __forceinline__ void stf(void* p, size_t i, float v) {
    if (B16) ((__hip_bfloat16*)p)[i] = __float2bfloat16(v);
    else     ((float*)p)[i] = v;
}
template<bool B16>
static __device__ __forceinline__ float4 ld4(const void* p, size_t i4) {
    if (B16) {
        uint2 u = ((const uint2*)p)[i4];
        return make_float4(__uint_as_float(u.x << 16), __uint_as_float(u.x & 0xffff0000u),
                           __uint_as_float(u.y << 16), __uint_as_float(u.y & 0xffff0000u));
    } else {
        return ((const float4*)p)[i4];
    }
}
template<bool B16>
static __device__ __forceinline__ void st4(void* p, size_t i4, float4 v) {
    if (B16) {
        stf<true>(p, 4*i4 + 0, v.x); stf<true>(p, 4*i4 + 1, v.y);
        stf<true>(p, 4*i4 + 2, v.z); stf<true>(p, 4*i4 + 3, v.w);
    } else {
        ((float4*)p)[i4] = v;
    }
}
static __device__ __forceinline__ unsigned short f2bf_bits(float x) {
    __hip_bfloat16 b = __float2bfloat16(x);
    return *reinterpret_cast<unsigned short*>(&b);
}
static __device__ __forceinline__ uint32_t pack_bf2(float lo, float hi) {
    return (uint32_t)f2bf_bits(lo) | ((uint32_t)f2bf_bits(hi) << 16);
}
static __device__ __forceinline__ short bfs(float x) {
    unsigned short u = f2bf_bits(x);
    return *reinterpret_cast<short*>(&u);
}
// runtime-dtype vector load/store (isb: 1 = tensors bf16, 0 = f32)
static __device__ __forceinline__ float4 ld4rt(const void* p, size_t i4, int isb) {
    if (isb) {
        uint2 u = ((const uint2*)p)[i4];
        return make_float4(__uint_as_float(u.x << 16), __uint_as_float(u.x & 0xffff0000u),
                           __uint_as_float(u.y << 16), __uint_as_float(u.y & 0xffff0000u));
    }
    return ((const float4*)p)[i4];
}
static __device__ __forceinline__ void st4rt(void* p, size_t i4, float4 v, int isb) {
    if (isb) {
        ((uint2*)p)[i4] = make_uint2(pack_bf2(v.x, v.y), pack_bf2(v.z, v.w));
    } else {
        ((float4*)p)[i4] = v;
    }
}

static __device__ __forceinline__ f32x4 mfma32(bf16x8 a, bf16x8 b, f32x4 c) {
    return __builtin_amdgcn_mfma_f32_16x16x32_bf16(a, b, c, 0, 0, 0);
}
static __device__ __forceinline__ f32x4 mfma16(bf16x4 a, bf16x4 b, f32x4 c) {
#if defined(__has_builtin)
#if __has_builtin(__builtin_amdgcn_mfma_f32_16x16x16bf16_1k)
    return __builtin_amdgcn_mfma_f32_16x16x16bf16_1k(a, b, c, 0, 0, 0);
#define MFMA16_DONE 1
#endif
#endif
#ifndef MFMA16_DONE
    asm volatile("v_mfma_f32_16x16x16_bf16 %0, %1, %2, %0\n\ts_nop 7\n\ts_nop 7"
                 : "+v"(c) : "v"(a), "v"(b));
    return c;
#endif
}

// ---- dtype sniff: P(wrong) ~ 0.48^128 ----
__global__ void sniff_kernel(const uint32_t* __restrict__ w, float* __restrict__ ws) {
    int bad = 0;
    for (int i = 0; i < 128; ++i) {
        uint32_t d = w[i];
        float a = __uint_as_float(d << 16);
        float b = __uint_as_float(d & 0xffff0000u);
        if (!(fabsf(a) <= 0.1f)) bad++;
        if (!(fabsf(b) <= 0.1f)) bad++;
    }
    ((int*)ws)[O_FLAG] = (bad == 0) ? 1 : 0;
}

// ---- weights -> fp32 in ws; W2/Wn2/WC1T transposed ----
__global__ void prep_kernel(
    const void* We1, const void* be1, const void* We2, const void* be2,
    const void* Wn1, const void* bn1, const void* Wn2, const void* bn2,
    const void* Wc1, const void* bc1, const void* Wc2, const void* bc2,
    float* __restrict__ wf)
{
    const int isb = ((const int*)wf)[O_FLAG];
    int tid = blockIdx.x * blockDim.x + threadIdx.x;
    int stride = gridDim.x * blockDim.x;
#define LD(src, i) (isb ? bf2f(((const __hip_bfloat16*)(src))[i]) : ((const float*)(src))[i])
#define CP(dst, src, n)  for (int i = tid; i < (n); i += stride) wf[(dst) + i] = LD(src, i);
#define CPT(dst, src)    for (int i = tid; i < 4096; i += stride) \
        wf[(dst) + (i & 63) * 64 + (i >> 6)] = LD(src, i);
    CP(O_W1,  We1, 129*64)  CP(O_B1,  be1, 64)
    CPT(O_W2,  We2)         CP(O_B2,  be2, 64)
    CP(O_WC1, Wc1, 64*64)   CP(O_BC1, bc1, 64)
    CPT(O_WC1T, Wc1)
    CP(O_WC2, Wc2, 64)      CP(O_BC2, bc2, 1)
    CP(O_WN1, Wn1, 128*64)  CP(O_BN1, bn1, 64)
    CPT(O_WN2, Wn2)         CP(O_BN2, bn2, 64)
#undef CP
#undef CPT
#undef LD
}

// ---- R11 (HW-verified): MFMA pre_edge — Y^T = We1^T @ h^T (+b1 on row half).
__global__ __launch_bounds__(256, 3) void pre_edge_kernel(
    const void* __restrict__ h, float* __restrict__ ws)
{
    const int isb = ((const int*)ws)[O_FLAG];
    __shared__ bf16x8 s_wh[16][64];                // We1^T frags [2t+s][lane]
    __shared__ bf16x8 s_wl[16][64];
    __shared__ __align__(16) float s_b1[64];

    const int tid = threadIdx.x;
    for (int f = tid; f < 1024; f += 256) {
        int frag = f >> 6, l = f & 63;
        int t = frag >> 1, s = frag & 1, e2 = l & 15, g2 = l >> 4;
        const float* p = ws + O_W1 + (size_t)((t >= 4 ? 64 : 0) + 32*s + 8*g2) * 64
                         + 16*(t & 3) + e2;
        bf16x8 rh, rl;
        #pragma unroll
        for (int j = 0; j < 8; ++j) {
            float w = p[j * 64];
            unsigned short hb = f2bf_bits(w);
            rh[j] = (short)hb;
            rl[j] = bfs(w - __uint_as_float((uint32_t)hb << 16));
        }
        s_wh[frag][l] = rh; s_wl[frag][l] = rl;
    }
    for (int i = tid; i < 64; i += 256) s_b1[i] = ws[O_B1 + i];
    __syncthreads();

    const int lane = tid & 63, e = lane & 15, g = lane >> 4;
    const int c = blockIdx.x * 4 + (tid >> 6);
    if (c >= NN / 16) return;
    asm volatile("" ::: "memory");                 // keep LDS reads below (R8 lesson)
    const int n = c * 16 + e;

    bf16x8 bhi[2], blo[2];
    #pragma unroll
    for (int s = 0; s < 2; ++s) {
        float4 a0 = ld4rt(h, (size_t)n * 16 + 8*s + 2*g, isb);
        float4 a1 = ld4rt(h, (size_t)n * 16 + 8*s + 2*g + 1, isb);
        float a[8] = {a0.x, a0.y, a0.z, a0.w, a1.x, a1.y, a1.z, a1.w};
        bf16x8 h8, l8;
        #pragma unroll
        for (int j = 0; j < 8; ++j) {
            unsigned short hb = f2bf_bits(a[j]);
            h8[j] = (short)hb;
            l8[j] = bfs(a[j] - __uint_as_float((uint32_t)hb << 16));
        }
        bhi[s] = h8; blo[s] = l8;
    }

    #pragma unroll
    for (int t = 0; t < 8; ++t) {
        f32x4 d;
        if (t < 4) d = *(const f32x4*)&s_b1[16*t + 4*g];
        else       d = (f32x4){0.0f, 0.0f, 0.0f, 0.0f};
        #pragma unroll
        for (int s = 0; s < 2; ++s) {
            bf16x8 wh = s_wh[2*t + s][lane];
            bf16x8 wl = s_wl[2*t + s][lane];
            d = mfma32(wh, bhi[s], d);
            d = mfma32(wh, blo[s], d);
            d = mfma32(wl, bhi[s], d);
        }
        *(float4*)(ws + O_Y + (size_t)n * 128 + 16*t + 4*g) =
            make_float4(d[0], d[1], d[2], d[3]);
    }
}

// ---- edge MLP scalar core (atomic-fallback only) ----
template<bool B16>
static __device__ __forceinline__ void edge_mlp(
    const void* __restrict__ coord, const float* __restrict__ wf,
    int row, int col,
    float4 efbuf[16], float& gate, float& cdx, float& cdy, float& cdz)
{
    cdx = ldf<B16>(coord, 3*row + 0) - ldf<B16>(coord, 3*col + 0);
    cdy = ldf<B16>(coord, 3*row + 1) - ldf<B16>(coord, 3*col + 1);
    cdz = ldf<B16>(coord, 3*row + 2) - ldf<B16>(coord, 3*col + 2);
    float radial = cdx*cdx + cdy*cdy + cdz*cdz;

    const float4* yrv = (const float4*)(wf + O_Y + (size_t)row * 128);
    const float4* ycv = (const float4*)(wf + O_Y + (size_t)col * 128 + 64);

    float acc[64];
    #pragma unroll
    for (int q = 0; q < 16; ++q) {
        float4 a = yrv[q];
        float4 b = ycv[q];
        const float* wr = wf + O_W1 + 128 * 64 + q * 4;
        acc[4*q+0] = fmaxf(fmaf(radial, wr[0], a.x + b.x), 0.0f);
        acc[4*q+1] = fmaxf(fmaf(radial, wr[1], a.y + b.y), 0.0f);
        acc[4*q+2] = fmaxf(fmaf(radial, wr[2], a.z + b.z), 0.0f);
        acc[4*q+3] = fmaxf(fmaf(radial, wr[3], a.w + b.w), 0.0f);
    }

    #pragma unroll
    for (int j0 = 0; j0 < 16; ++j0) {
        float c[4];
        #pragma unroll
        for (int u = 0; u < 4; ++u) {
            int j = j0 * 4 + u;
            float t = wf[O_B2 + j];
            const float* w2t = wf + O_W2 + j * 64;
            #pragma unroll
            for (int k = 0; k < 64; ++k) t = fmaf(acc[k], w2t[k], t);
            c[u] = fmaxf(t, 0.0f);
        }
        efbuf[j0] = make_float4(c[0], c[1], c[2], c[3]);
    }

    float hid[64];
    #pragma unroll
    for (int j = 0; j < 64; ++j) hid[j] = wf[O_BC1 + j];
    #pragma unroll
    for (int j0 = 0; j0 < 16; ++j0) {
        float4 ef4 = efbuf[j0];
        const float* w0 = wf + O_WC1 + (j0 * 4 + 0) * 64;
        const float* w1 = wf + O_WC1 + (j0 * 4 + 1) * 64;
        const float* w2 = wf + O_WC1 + (j0 * 4 + 2) * 64;
        const float* w3 = wf + O_WC1 + (j0 * 4 + 3) * 64;
        #pragma unroll
        for (int jj = 0; jj < 64; ++jj) hid[jj] = fmaf(ef4.x, w0[jj], hid[jj]);
        #pragma unroll
        for (int jj = 0; jj < 64; ++jj) hid[jj] = fmaf(ef4.y, w1[jj], hid[jj]);
        #pragma unroll
        for (int jj = 0; jj < 64; ++jj) hid[jj] = fmaf(ef4.z, w2[jj], hid[jj]);
        #pragma unroll
        for (int jj = 0; jj < 64; ++jj) hid[jj] = fmaf(ef4.w, w3[jj], hid[jj]);
    }

    float g0 = wf[O_BC2], g1 = 0.0f, g2 = 0.0f, g3 = 0.0f;
    #pragma unroll
    for (int j = 0; j < 64; j += 4) {
        g0 = fmaf(fmaxf(hid[j + 0], 0.0f), wf[O_WC2 + j + 0], g0);
        g1 = fmaf(fmaxf(hid[j + 1], 0.0f), wf[O_WC2 + j + 1], g1);
        g2 = fmaf(fmaxf(hid[j + 2], 0.0f), wf[O_WC2 + j + 2], g2);
        g3 = fmaf(fmaxf(hid[j + 3], 0.0f), wf[O_WC2 + j + 3], g3);
    }
    gate = (g0 + g1) + (g2 + g3);
}

// ============ CSR path ============
__global__ __launch_bounds__(256) void count_kernel(
    const int* __restrict__ ei, float* __restrict__ ws)
{
    int e = blockIdx.x * 256 + threadIdx.x;
    if (e >= NE) return;
    atomicAdd((int*)ws + N_CNT + ei[e], 1);
}

// R12 (HW-verified): 4 elements/thread, 13 iterations.
__global__ __launch_bounds__(1024) void scan_kernel(float* __restrict__ ws) {
    int* cnt = (int*)ws + N_CNT;
    int* off = (int*)ws + N_OFF;
    __shared__ int wsum[16];
    __shared__ int carry_s;
    int tid = threadIdx.x, lane = tid & 63, wid = tid >> 6;
    if (tid == 0) carry_s = 0;
    __syncthreads();
    for (int base = 0; base < NN; base += 4096) {
        int i0 = base + tid * 4;
        int a0 = (i0 + 0 < NN) ? cnt[i0 + 0] : 0;
        int a1 = (i0 + 1 < NN) ? cnt[i0 + 1] : 0;
        int a2 = (i0 + 2 < NN) ? cnt[i0 + 2] : 0;
        int a3 = (i0 + 3 < NN) ? cnt[i0 + 3] : 0;
        int tsum = ((a0 + a1) + (a2 + a3));
        int v = tsum;
        #pragma unroll
        for (int s = 1; s < 64; s <<= 1) { int t = __shfl_up(v, s, 64); if (lane >= s) v += t; }
        if (lane == 63) wsum[wid] = v;
        __syncthreads();
        if (wid == 0) {
            int w = (lane < 16) ? wsum[lane] : 0;
            #pragma unroll
            for (int s = 1; s < 16; s <<= 1) { int t = __shfl_up(w, s, 64); if (lane >= s) w += t; }
            if (lane < 16) wsum[lane] = w;
        }
        __syncthreads();
        int waveback = (wid > 0) ? wsum[wid - 1] : 0;
        int excl = carry_s + waveback + (v - tsum);
        if (i0 + 0 < NN) { off[i0 + 0] = excl; cnt[i0 + 0] = excl; }
        excl += a0;
        if (i0 + 1 < NN) { off[i0 + 1] = excl; cnt[i0 + 1] = excl; }
        excl += a1;
        if (i0 + 2 < NN) { off[i0 + 2] = excl; cnt[i0 + 2] = excl; }
        excl += a2;
        if (i0 + 3 < NN) { off[i0 + 3] = excl; cnt[i0 + 3] = excl; }
        __syncthreads();
        if (tid == 0) carry_s += wsum[15];
        __syncthreads();
    }
    if (threadIdx.x == 0) off[NN] = carry_s;
}

// store col only (4B) — row is implicit in the node-based edge kernel.
__global__ __launch_bounds__(256) void scatter_kernel(
    const int* __restrict__ ei, float* __restrict__ ws)
{
    int e = blockIdx.x * 256 + threadIdx.x;
    if (e >= NE) return;
    int row = ei[e];
    int col = ei[NE + e];
    int pos = atomicAdd((int*)ws + N_CNT + row, 1);
    ((int*)ws + N_RC)[pos] = col;
}

// ---- R18: node-based MFMA edge kernel with FUSED aggregation.
// R13 post-mortem: (256,6) capped VGPR at 40 < the ~64-reg live set ->
// loop-carried scalars spilled (WRITE 14->343MB, 110.9->191us despite Occ 59%).
// Occupancy converts ONLY while 512/waves >= live-set. R18: (256,4) ->
// VGPR cap 128 >> 64 (no spill), occupancy cap 50% (vs R12's 34%).
// Chunk-loop fence + full scalarization retained (R12-proven).
#define SPLIT1(H, L, IDX, VAL, WI) { \
    float _v = fmaxf(fmaf(radial, s_w1r[WI], (VAL)), 0.0f); \
    unsigned short _hb = f2bf_bits(_v); \
    H[IDX] = (short)_hb; \
    L[IDX] = bfs(_v - __uint_as_float((uint32_t)_hb << 16)); }
#define SPLIT8(H, L, WOFF, V0,V1,V2,V3,V4,V5,V6,V7) \
    SPLIT1(H,L,0,V0,(WOFF)+0) SPLIT1(H,L,1,V1,(WOFF)+1) \
    SPLIT1(H,L,2,V2,(WOFF)+2) SPLIT1(H,L,3,V3,(WOFF)+3) \
    SPLIT1(H,L,4,V4,(WOFF)+4) SPLIT1(H,L,5,V5,(WOFF)+5) \
    SPLIT1(H,L,6,V6,(WOFF)+6) SPLIT1(H,L,7,V7,(WOFF)+7)
#define PHASEB(D, T) { \
    bf16x8 wh0 = s_wbh[2*(T)+0][lane], wh1 = s_wbh[2*(T)+1][lane]; \
    bf16x8 wl0 = s_wbl[2*(T)+0][lane], wl1 = s_wbl[2*(T)+1][lane]; \
    D = mfma32(wh0, ahi0, D); D = mfma32(wh1, ahi1, D); \
    D = mfma32(wh0, alo0, D); D = mfma32(wh1, alo1, D); \
    D = mfma32(wl0, ahi0, D); D = mfma32(wl1, ahi1, D); }
#define EFBLK(D, BQ, A0,A1,A2,A3) { \
    float _e0 = fmaxf(D[0], 0.0f) * vmask; \
    float _e1 = fmaxf(D[1], 0.0f) * vmask; \
    float _e2 = fmaxf(D[2], 0.0f) * vmask; \
    float _e3 = fmaxf(D[3], 0.0f) * vmask; \
    BQ[0] = (short)f2bf_bits(_e0); BQ[1] = (short)f2bf_bits(_e1); \
    BQ[2] = (short)f2bf_bits(_e2); BQ[3] = (short)f2bf_bits(_e3); \
    A0 += _e0; A1 += _e1; A2 += _e2; A3 += _e3; }
#define PHASEC(D, U) { \
    D = mfma16(s_wc[4*(U)+0][lane], bq0, D); \
    D = mfma16(s_wc[4*(U)+1][lane], bq1, D); \
    D = mfma16(s_wc[4*(U)+2][lane], bq2, D); \
    D = mfma16(s_wc[4*(U)+3][lane], bq3, D); }
#define GATEU(D, U) { \
    gp = fmaf(fmaxf(D[0], 0.0f), s_wc2[16*(U) + 4*g + 0], gp); \
    gp = fmaf(fmaxf(D[1], 0.0f), s_wc2[16*(U) + 4*g + 1], gp); \
    gp = fmaf(fmaxf(D[2], 0.0f), s_wc2[16*(U) + 4*g + 2], gp); \
    gp = fmaf(fmaxf(D[3], 0.0f), s_wc2[16*(U) + 4*g + 3], gp); }
#define RED16(M) \
    ag00 += __shfl_xor(ag00,M,64); ag01 += __shfl_xor(ag01,M,64); \
    ag02 += __shfl_xor(ag02,M,64); ag03 += __shfl_xor(ag03,M,64); \
    ag10 += __shfl_xor(ag10,M,64); ag11 += __shfl_xor(ag11,M,64); \
    ag12 += __shfl_xor(ag12,M,64); ag13 += __shfl_xor(ag13,M,64); \
    ag20 += __shfl_xor(ag20,M,64); ag21 += __shfl_xor(ag21,M,64); \
    ag22 += __shfl_xor(ag22,M,64); ag23 += __shfl_xor(ag23,M,64); \
    ag30 += __shfl_xor(ag30,M,64); ag31 += __shfl_xor(ag31,M,64); \
    ag32 += __shfl_xor(ag32,M,64); ag33 += __shfl_xor(ag33,M,64);

__global__ __launch_bounds__(256, 4) void edge_csr_kernel(
    const void* __restrict__ coord, float* __restrict__ ws)
{
    const int isb = ((const int*)ws)[O_FLAG];

    __shared__ bf16x8 s_wbh[8][64];                // We2^T hi frags [2t+s][lane], 8KB
    __shared__ bf16x8 s_wbl[8][64];                // We2^T lo frags, 8KB
    __shared__ bf16x4 s_wc[16][64];                // Wc1^T frags [4u+t][lane], 8KB
    __shared__ __align__(16) float s_b2[64];
    __shared__ __align__(16) float s_bc1[64];
    __shared__ __align__(16) float s_wc2[64];
    __shared__ float s_w1r[64];
    __shared__ float s_bc2v;

    const int tid = threadIdx.x;
    for (int f = tid; f < 512; f += 256) {         // We2^T hi/lo fill
        int frag = f >> 6, l = f & 63;
        int t = frag >> 1, s = frag & 1, e2 = l & 15, g2 = l >> 4;
        const float* p = ws + O_W2 + (16*t + e2)*64 + 32*s + 8*g2;
        bf16x8 rh, rl;
        #pragma unroll
        for (int j = 0; j < 8; ++j) {
            float w = p[j];
            unsigned short hb = f2bf_bits(w);
            rh[j] = (short)hb;
            float hf = __uint_as_float((uint32_t)hb << 16);
            rl[j] = bfs(w - hf);
        }
        s_wbh[frag][l] = rh;
        s_wbl[frag][l] = rl;
    }
    for (int f = tid; f < 1024; f += 256) {        // Wc1^T fill (hi only)
        int frag = f >> 6, l = f & 63;
        int u = frag >> 2, t = frag & 3, e2 = l & 15, g2 = l >> 4;
        const float* p = ws + O_WC1T + (16*u + e2)*64 + 16*t + 4*g2;
        bf16x4 r;
        #pragma unroll
        for (int j = 0; j < 4; ++j) r[j] = bfs(p[j]);
        s_wc[frag][l] = r;
    }
    for (int i = tid; i < 64; i += 256) {
        s_b2[i]  = ws[O_B2 + i];
        s_bc1[i] = ws[O_BC1 + i];
        s_wc2[i] = ws[O_WC2 + i];
        s_w1r[i] = ws[O_W1 + 128*64 + i];          // radial row of We1
    }
    if (tid == 0) s_bc2v = ws[O_BC2];
    __syncthreads();

    const int lane = threadIdx.x & 63;
    const int e = lane & 15, g = lane >> 4;
    const int wid = blockIdx.x * 4 + (int)(threadIdx.x >> 6);
    const int nw = 4096;                           // grid is exactly 1024 blocks
    const int* off = (const int*)ws + N_OFF;
    const int* colA = (const int*)ws + N_RC;
    const float* cf = (const float*)coord;
    const __hip_bfloat16* cbh = (const __hip_bfloat16*)coord;

    for (int n = wid; n < NN; n += nw) {
        const int s0 = off[n], s1 = off[n + 1];

        // node (row) coords — wave-uniform
        float crx, cry, crz;
        if (isb) {
            crx = bf2f(cbh[3*n+0]); cry = bf2f(cbh[3*n+1]); crz = bf2f(cbh[3*n+2]);
        } else {
            crx = cf[3*n+0]; cry = cf[3*n+1]; crz = cf[3*n+2];
        }
        // row-half Y (k = 32s + 8g + j) — uniform across e-lanes; SCALARIZED
        float y00, y01, y02, y03, y04, y05, y06, y07;
        float y10, y11, y12, y13, y14, y15, y16, y17;
        {
            const float4* yr4 = (const float4*)(ws + O_Y + (size_t)n * 128 + 8*g);
            float4 ra = yr4[0], rb = yr4[1];
            y00=ra.x; y01=ra.y; y02=ra.z; y03=ra.w;
            y04=rb.x; y05=rb.y; y06=rb.z; y07=rb.w;
        }
        {
            const float4* yr4 = (const float4*)(ws + O_Y + (size_t)n * 128 + 32 + 8*g);
            float4 ra = yr4[0], rb = yr4[1];
            y10=ra.x; y11=ra.y; y12=ra.z; y13=ra.w;
            y14=rb.x; y15=rb.y; y16=rb.z; y17=rb.w;
        }

        // SCALARIZED accumulators (rule #20 hard-proofing)
        float ag00=0.f, ag01=0.f, ag02=0.f, ag03=0.f;
        float ag10=0.f, ag11=0.f, ag12=0.f, ag13=0.f;
        float ag20=0.f, ag21=0.f, ag22=0.f, ag23=0.f;
        float ag30=0.f, ag31=0.f, ag32=0.f, ag33=0.f;
        float tx = 0.0f, ty = 0.0f, tz = 0.0f;

        for (int base = s0; base < s1; base += 16) {
            // anti-LICM fence INSIDE the weight-consuming loop (R12-proven
            // placement; a node-level fence lets LICM hoist the LDS weight
            // reads out of this loop -> spill -> GB-scale scratch traffic).
            asm volatile("" ::: "memory");

            const int cnt = s1 - base;             // >= 1 here
            const bool valid = e < cnt;
            const int col = colA[base + (valid ? e : 0)];

            float ccx, ccy, ccz;
            if (isb) {
                ccx = bf2f(cbh[3*col+0]); ccy = bf2f(cbh[3*col+1]); ccz = bf2f(cbh[3*col+2]);
            } else {
                ccx = cf[3*col+0]; ccy = cf[3*col+1]; ccz = cf[3*col+2];
            }
            float cdx = crx - ccx, cdy = cry - ccy, cdz = crz - ccz;
            float radial = cdx*cdx + cdy*cdy + cdz*cdz;

            // acc (k = 32s + 8g + j) in fp32, split hi/lo bf16 — SCALARIZED
            const float* Yc = ws + O_Y + (size_t)col * 128 + 64;
            bf16x8 ahi0, alo0, ahi1, alo1;
            {
                const float4* yc4 = (const float4*)(Yc + 8*g);
                float4 ca = yc4[0], cb4 = yc4[1];
                SPLIT8(ahi0, alo0, 8*g,
                       y00+ca.x, y01+ca.y, y02+ca.z, y03+ca.w,
                       y04+cb4.x, y05+cb4.y, y06+cb4.z, y07+cb4.w)
            }
            {
                const float4* yc4 = (const float4*)(Yc + 32 + 8*g);
                float4 ca = yc4[0], cb4 = yc4[1];
                SPLIT8(ahi1, alo1, 32 + 8*g,
                       y10+ca.x, y11+ca.y, y12+ca.z, y13+ca.w,
                       y14+cb4.x, y15+cb4.y, y16+cb4.z, y17+cb4.w)
            }

            // phase B: D1[ef][edge], C-init = b2; 3-product hi/lo
            f32x4 d10 = *(const f32x4*)&s_b2[ 0 + 4*g];
            f32x4 d11 = *(const f32x4*)&s_b2[16 + 4*g];
            f32x4 d12 = *(const f32x4*)&s_b2[32 + 4*g];
            f32x4 d13 = *(const f32x4*)&s_b2[48 + 4*g];
            PHASEB(d10, 0) PHASEB(d11, 1) PHASEB(d12, 2) PHASEB(d13, 3)

            // relu (fp32) + validity mask; bq = bf16(ef) for the gate path
            const float vmask = valid ? 1.0f : 0.0f;
            bf16x4 bq0, bq1, bq2, bq3;
            EFBLK(d10, bq0, ag00, ag01, ag02, ag03)
            EFBLK(d11, bq1, ag10, ag11, ag12, ag13)
            EFBLK(d12, bq2, ag20, ag21, ag22, ag23)
            EFBLK(d13, bq3, ag30, ag31, ag32, ag33)

            // phase C: D2[hid][edge] = Wc1^T @ ef^T, C-init = bc1
            f32x4 d20 = *(const f32x4*)&s_bc1[ 0 + 4*g];
            f32x4 d21 = *(const f32x4*)&s_bc1[16 + 4*g];
            f32x4 d22 = *(const f32x4*)&s_bc1[32 + 4*g];
            f32x4 d23 = *(const f32x4*)&s_bc1[48 + 4*g];
            PHASEC(d20, 0) PHASEC(d21, 1) PHASEC(d22, 2) PHASEC(d23, 3)

            // gate = bc2 + sum_h relu(hid[h]) * Wc2[h]; reduce over 4 g-groups
            float gp = 0.0f;
            GATEU(d20, 0) GATEU(d21, 1) GATEU(d22, 2) GATEU(d23, 3)
            gp += __shfl_xor(gp, 16, 64);
            gp += __shfl_xor(gp, 32, 64);
            float gate = gp + s_bc2v;

            if (valid && g == 0) {
                tx += fminf(fmaxf(cdx * gate, -100.0f), 100.0f);
                ty += fminf(fmaxf(cdy * gate, -100.0f), 100.0f);
                tz += fminf(fmaxf(cdz * gate, -100.0f), 100.0f);
            }
        }

        // cross-edge reduce of agg (over e-lanes, within each g-group)
        RED16(1) RED16(2) RED16(4) RED16(8)

        // write agg row: lane (e=t, g) stores features 16t+4g+{0..3}
        float* aggw = ws + N_AGGH + (size_t)n * 64;
        if (e == 0)      *(float4*)(aggw + 0  + 4*g) = make_float4(ag00, ag01, ag02, ag03);
        else if (e == 1) *(float4*)(aggw + 16 + 4*g) = make_float4(ag10, ag11, ag12, ag13);
        else if (e == 2) *(float4*)(aggw + 32 + 4*g) = make_float4(ag20, ag21, ag22, ag23);
        else if (e == 3) *(float4*)(aggw + 48 + 4*g) = make_float4(ag30, ag31, ag32, ag33);

        // cross-edge reduce of trans (g==0 lanes hold partials)
        tx += __shfl_xor(tx, 1, 64); ty += __shfl_xor(ty, 1, 64); tz += __shfl_xor(tz, 1, 64);
        tx += __shfl_xor(tx, 2, 64); ty += __shfl_xor(ty, 2, 64); tz += __shfl_xor(tz, 2, 64);
        tx += __shfl_xor(tx, 4, 64); ty += __shfl_xor(ty, 4, 64); tz += __shfl_xor(tz, 4, 64);
        tx += __shfl_xor(tx, 8, 64); ty += __shfl_xor(ty, 8, 64); tz += __shfl_xor(tz, 8, 64);
        if (lane == 0) {
            ws[N_SUMT + 3*(size_t)n + 0] = tx;
            ws[N_SUMT + 3*(size_t)n + 1] = ty;
            ws[N_SUMT + 3*(size_t)n + 2] = tz;
        }
    }
}
#undef SPLIT1
#undef SPLIT8
#undef PHASEB
#undef EFBLK
#undef PHASEC
#undef GATEU
#undef RED16

// ---- scalar node core (atomic fallback only) ----
template<bool B16>
static __device__ __forceinline__ void node_core(
    const void* __restrict__ h, const void* __restrict__ coord,
    const void* __restrict__ vel, const float* __restrict__ ws,
    const float* __restrict__ agg, const float* __restrict__ sumt, float cntf,
    void* __restrict__ out, int n)
{
    float inv = (cntf > 0.0f) ? (1.0f / fmaxf(cntf, 1.0f)) : 0.0f;
    #pragma unroll
    for (int i = 0; i < 3; ++i) {
        float aggc = sumt[3*n + i] * inv;
        float v = ldf<B16>(vel, 3*n + i) + aggc * 0.125f;
        float cn = ldf<B16>(coord, 3*n + i) + v * 0.125f;
        stf<B16>(out, OUT_COORD + 3*n + i, cn);
        stf<B16>(out, OUT_V + 3*n + i, v);
    }

    float acc[64];
    #pragma unroll
    for (int j = 0; j < 64; ++j) acc[j] = ws[O_BN1 + j];

    #pragma unroll 4
    for (int q = 0; q < 16; ++q) {
        float4 a = ld4<B16>(h, (size_t)n * 16 + q);
        const float* w = ws + O_WN1 + (q * 4) * 64;
        #pragma unroll
        for (int j = 0; j < 64; ++j) acc[j] = fmaf(a.x, w[j], acc[j]);
        #pragma unroll
        for (int j = 0; j < 64; ++j) acc[j] = fmaf(a.y, w[64 + j], acc[j]);
        #pragma unroll
        for (int j = 0; j < 64; ++j) acc[j] = fmaf(a.z, w[128 + j], acc[j]);
        #pragma unroll
        for (int j = 0; j < 64; ++j) acc[j] = fmaf(a.w, w[192 + j], acc[j]);
    }
    const float4* agv = (const float4*)(agg + (size_t)n * 64);
    #pragma unroll 4
    for (int q = 0; q < 16; ++q) {
        float4 a = agv[q];
        const float* w = ws + O_WN1 + (64 + q * 4) * 64;
        #pragma unroll
        for (int j = 0; j < 64; ++j) acc[j] = fmaf(a.x, w[j], acc[j]);
        #pragma unroll
        for (int j = 0; j < 64; ++j) acc[j] = fmaf(a.y, w[64 + j], acc[j]);
        #pragma unroll
        for (int j = 0; j < 64; ++j) acc[j] = fmaf(a.z, w[128 + j], acc[j]);
        #pragma unroll
        for (int j = 0; j < 64; ++j) acc[j] = fmaf(a.w, w[192 + j], acc[j]);
    }
    #pragma unroll
    for (int j = 0; j < 64; ++j) acc[j] = fmaxf(acc[j], 0.0f);

    float4 ob[16];
    #pragma unroll
    for (int j0 = 0; j0 < 16; ++j0) {
        float4 hres = ld4<B16>(h, (size_t)n * 16 + j0);
        float c[4];
        #pragma unroll
        for (int u = 0; u < 4; ++u) {
            int j = j0 * 4 + u;
            float t = ws[O_BN2 + j];
            const float* w = ws + O_WN2 + j * 64;
            #pragma unroll
            for (int k = 0; k < 64; ++k) t = fmaf(acc[k], w[k], t);
            c[u] = t;
        }
        ob[j0] = make_float4(hres.x + c[0], hres.y + c[1], hres.z + c[2], hres.w + c[3]);
    }
    #pragma unroll
    for (int j0 = 0; j0 < 16; ++j0) st4<B16>(out, (size_t)n * 16 + j0, ob[j0]);
}

// ---- R11 (HW-verified): MFMA node kernel (CSR path, both dtypes).
__global__ __launch_bounds__(256, 3) void node_kernel_csr(
    const void* __restrict__ h, const void* __restrict__ coord,
    const void* __restrict__ vel, const float* __restrict__ ws,
    void* __restrict__ out)
{
    const int isb = ((const int*)ws)[O_FLAG];

    __shared__ bf16x8 s_w1h[16][64];               // Wn1^T frags [4t+s][lane], 16KB
    __shared__ bf16x8 s_w1l[16][64];               // 16KB
    __shared__ bf16x4 s_w2h[16][64];               // Wn2^T frags [4u+t][lane], 8KB
    __shared__ bf16x4 s_w2l[16][64];               // 8KB
    __shared__ __align__(16) float s_bn1[64];
    __shared__ __align__(16) float s_bn2[64];

    const int tid = threadIdx.x;
    for (int f = tid; f < 1024; f += 256) {        // Wn1^T hi/lo fill
        int frag = f >> 6, l = f & 63;
        int t = frag >> 2, s = frag & 3, e2 = l & 15, g2 = l >> 4;
        const float* p = ws + O_WN1 + (size_t)(32*s + 8*g2) * 64 + 16*t + e2;
        bf16x8 rh, rl;
        #pragma unroll
        for (int j = 0; j < 8; ++j) {
            float w = p[j * 64];
            unsigned short hb = f2bf_bits(w);
            rh[j] = (short)hb;
            rl[j] = bfs(w - __uint_as_float((uint32_t)hb << 16));
        }
        s_w1h[frag][l] = rh; s_w1l[frag][l] = rl;
    }
    for (int f = tid; f < 1024; f += 256) {        // Wn2^T hi/lo fill
        int frag = f >> 6, l = f & 63;
        int u = frag >> 2, t = frag & 3, e2 = l & 15, g2 = l >> 4;
        const float* p = ws + O_WN2 + (16*u + e2) * 64 + 16*t + 4*g2;
        bf16x4 rh, rl;
        #pragma unroll
        for (int j = 0; j < 4; ++j) {
            float w = p[j];
            unsigned short hb = f2bf_bits(w);
            rh[j] = (short)hb;
            rl[j] = bfs(w - __uint_as_float((uint32_t)hb << 16));
        }
        s_w2h[frag][l] = rh; s_w2l[frag][l] = rl;
    }
    for (int i = tid; i < 64; i += 256) { s_bn1[i] = ws[O_BN1 + i]; s_bn2[i] = ws[O_BN2 + i]; }
    __syncthreads();

    const int lane = tid & 63, e = lane & 15, g = lane >> 4;
    const int c = blockIdx.x * 4 + (tid >> 6);
    if (c >= NN / 16) return;
    asm volatile("" ::: "memory");                 // anti-LICM
    const int n = c * 16 + e;

    // coord / vel epilogue on g==0 lanes
    if (g == 0) {
        const int* off = (const int*)ws + N_OFF;
        float cntf = (float)(off[n + 1] - off[n]);
        float inv = (cntf > 0.0f) ? (1.0f / fmaxf(cntf, 1.0f)) : 0.0f;
        #pragma unroll
        for (int i = 0; i < 3; ++i) {
            float aggc = ws[N_SUMT + 3*n + i] * inv;
            float vv, cc;
            if (isb) {
                vv = bf2f(((const __hip_bfloat16*)vel)[3*n + i]);
                cc = bf2f(((const __hip_bfloat16*)coord)[3*n + i]);
            } else {
                vv = ((const float*)vel)[3*n + i];
                cc = ((const float*)coord)[3*n + i];
            }
            float v = vv + aggc * 0.125f;
            float cn = cc + v * 0.125f;
            if (isb) {
                ((__hip_bfloat16*)out)[OUT_COORD + 3*n + i] = __float2bfloat16(cn);
                ((__hip_bfloat16*)out)[OUT_V + 3*n + i] = __float2bfloat16(v);
            } else {
                ((float*)out)[OUT_COORD + 3*n + i] = cn;
                ((float*)out)[OUT_V + 3*n + i] = v;
            }
        }
    }

    // B-op: K=128 = h[0:64] ++ agg[0:64], hi/lo split (k = 32s + 8g + j)
    bf16x8 bhi[4], blo[4];
    #pragma unroll
    for (int s = 0; s < 4; ++s) {
        float a[8];
        if (s < 2) {
            float4 a0 = ld4rt(h, (size_t)n * 16 + 8*s + 2*g, isb);
            float4 a1 = ld4rt(h, (size_t)n * 16 + 8*s + 2*g + 1, isb);
            a[0]=a0.x; a[1]=a0.y; a[2]=a0.z; a[3]=a0.w;
            a[4]=a1.x; a[5]=a1.y; a[6]=a1.z; a[7]=a1.w;
        } else {
            const float4* ag = (const float4*)(ws + N_AGGH + (size_t)n * 64);
            float4 a0 = ag[8*(s-2) + 2*g];
            float4 a1 = ag[8*(s-2) + 2*g + 1];
            a[0]=a0.x; a[1]=a0.y; a[2]=a0.z; a[3]=a0.w;
            a[4]=a1.x; a[5]=a1.y; a[6]=a1.z; a[7]=a1.w;
        }
        bf16x8 h8, l8;
        #pragma unroll
        for (int j = 0; j < 8; ++j) {
            unsigned short hb = f2bf_bits(a[j]);
            h8[j] = (short)hb;
            l8[j] = bfs(a[j] - __uint_as_float((uint32_t)hb << 16));
        }
        bhi[s] = h8; blo[s] = l8;
    }

    // N1 (3-product hi/lo)
    f32x4 d1[4];
    #pragma unroll
    for (int t = 0; t < 4; ++t) d1[t] = *(const f32x4*)&s_bn1[16*t + 4*g];
    #pragma unroll
    for (int t = 0; t < 4; ++t) {
        #pragma unroll
        for (int s = 0; s < 4; ++s) {
            bf16x8 wh = s_w1h[4*t + s][lane];
            bf16x8 wl = s_w1l[4*t + s][lane];
            d1[t] = mfma32(wh, bhi[s], d1[t]);
            d1[t] = mfma32(wh, blo[s], d1[t]);
            d1[t] = mfma32(wl, bhi[s], d1[t]);
        }
    }

    // relu -> hi/lo fragments (features 16t+4g+{0..3})
    bf16x4 rhi[4], rlo[4];
    #pragma unroll
    for (int t = 0; t < 4; ++t) {
        #pragma unroll
        for (int j = 0; j < 4; ++j) {
            float v = fmaxf(d1[t][j], 0.0f);
            unsigned short hb = f2bf_bits(v);
            rhi[t][j] = (short)hb;
            rlo[t][j] = bfs(v - __uint_as_float((uint32_t)hb << 16));
        }
    }

    // N2 (3-product)
    f32x4 d2[4];
    #pragma unroll
    for (int u = 0; u < 4; ++u) d2[u] = *(const f32x4*)&s_bn2[16*u + 4*g];
    #pragma unroll
    for (int u = 0; u < 4; ++u) {
        #pragma unroll
        for (int t = 0; t < 4; ++t) {
            bf16x4 wh = s_w2h[4*u + t][lane];
            bf16x4 wl = s_w2l[4*u + t][lane];
            d2[u] = mfma16(wh, rhi[t], d2[u]);
            d2[u] = mfma16(wh, rlo[t], d2[u]);
            d2[u] = mfma16(wl, rhi[t], d2[u]);
        }
    }

    // residual + store (features 16u+4g+{0..3} -> float4 at h[n][16u+4g])
    #pragma unroll
    for (int u = 0; u < 4; ++u) {
        float4 hres = ld4rt(h, (size_t)n * 16 + 4*u + g, isb);
        float4 o = make_float4(hres.x + d2[u][0], hres.y + d2[u][1],
                               hres.z + d2[u][2], hres.w + d2[u][3]);
        st4rt(out, (size_t)n * 16 + 4*u + g, o, isb);
    }
}

// ============ atomic fallback (small ws) ============
template<bool B16>
static __device__ __forceinline__ void edge_atomic_core(
    const void* __restrict__ coord, const int* __restrict__ ei,
    float* __restrict__ ws, int e)
{
    int row = ei[e];
    int col = ei[NE + e];
    float gate, cdx, cdy, cdz;
    float4 efbuf[16];
    edge_mlp<B16>(coord, ws, row, col, efbuf, gate, cdx, cdy, cdz);

    float* ah = ws + F_AGGH + (size_t)row * 64;
    #pragma unroll
    for (int q = 0; q < 16; ++q) {
        unsafeAtomicAdd(&ah[4*q + 0], efbuf[q].x);
        unsafeAtomicAdd(&ah[4*q + 1], efbuf[q].y);
        unsafeAtomicAdd(&ah[4*q + 2], efbuf[q].z);
        unsafeAtomicAdd(&ah[4*q + 3], efbuf[q].w);
    }
    unsafeAtomicAdd(&ws[F_SUMT + 3*row + 0], fminf(fmaxf(cdx * gate, -100.0f), 100.0f));
    unsafeAtomicAdd(&ws[F_SUMT + 3*row + 1], fminf(fmaxf(cdy * gate, -100.0f), 100.0f));
    unsafeAtomicAdd(&ws[F_SUMT + 3*row + 2], fminf(fmaxf(cdz * gate, -100.0f), 100.0f));
    unsafeAtomicAdd(&ws[F_CNT + row], 1.0f);
}

__global__ __launch_bounds__(256, 2) void edge_atomic_kernel(
    const void* __restrict__ coord, const int* __restrict__ ei,
    float* __restrict__ ws)
{
    int e = blockIdx.x * 256 + threadIdx.x;
    if (e >= NE) return;
    if (((const int*)ws)[O_FLAG]) edge_atomic_core<true>(coord, ei, ws, e);
    else                          edge_atomic_core<false>(coord, ei, ws, e);
}

__global__ __launch_bounds__(256, 2) void node_kernel_atomic(
    const void* __restrict__ h, const void* __restrict__ coord,
    const void* __restrict__ vel, const float* __restrict__ ws,
    void* __restrict__ out)
{
    int n = blockIdx.x * 256 + threadIdx.x;
    if (n >= NN) return;
    float cntf = ws[F_CNT + n];
    if (((const int*)ws)[O_FLAG])
        node_core<true>(h, coord, vel, ws, ws + F_AGGH, ws + F_SUMT, cntf, out, n);
    else
        node_core<false>(h, coord, vel, ws, ws + F_AGGH, ws + F_SUMT, cntf, out, n);
}

extern "C" void kernel_launch(void* const* d_in, const int* in_sizes, int n_in,
                              void* d_out, int out_size, void* d_ws, size_t ws_size,
                              hipStream_t stream) {
    const void* h     = d_in[0];
    const void* coord = d_in[1];
    const void* vel   = d_in[2];
    const int* eidx = (const int*)d_in[4];
    float* ws = (float*)d_ws;

    sniff_kernel<<<1, 1, 0, stream>>>((const uint32_t*)d_in[5], ws);
    prep_kernel<<<64, 256, 0, stream>>>(d_in[5], d_in[6], d_in[7], d_in[8],
                                        d_in[9], d_in[10], d_in[11], d_in[12],
                                        d_in[13], d_in[14], d_in[15], d_in[16], ws);
    // 3125 16-node chunks, 4 waves/block -> 782 blocks
    pre_edge_kernel<<<782, 256, 0, stream>>>(h, ws);

    const bool big = ws_size >= (size_t)N_TOTAL * sizeof(float);
    if (big) {
        hipMemsetAsync((char*)d_ws + (size_t)N_CNT * 4, 0, (size_t)NN * 4, stream);
        count_kernel<<<(NE + 255) / 256, 256, 0, stream>>>(eidx, ws);
        scan_kernel<<<1, 1024, 0, stream>>>(ws);
        scatter_kernel<<<(NE + 255) / 256, 256, 0, stream>>>(eidx, ws);
        edge_csr_kernel<<<1024, 256, 0, stream>>>(coord, ws);
        node_kernel_csr<<<782, 256, 0, stream>>>(h, coord, vel, ws, d_out);
    } else {
        hipMemsetAsync((char*)d_ws + (size_t)F_AGGH * 4, 0,
                       (size_t)(F_TOTAL - F_AGGH) * 4, stream);
        edge_atomic_kernel<<<(NE + 255) / 256, 256, 0, stream>>>(coord, eidx, ws);
        node_kernel_atomic<<<(NN + 255) / 256, 256, 0, stream>>>(h, coord, vel, ws, d_out);
    }
}

// Round 15
// 344.470 us; speedup vs baseline: 1.2719x; 1.0279x over previous
//
#include <hip/hip_runtime.h>
#include <hip/hip_bf16.h>
#include <stdint.h>

#define NE 800000
#define NN 50000
#define PRE_BLOCKS 782   // pre_edge blocks (3125 chunks / 4 waves); count blocks follow

// ---- weight region (float offsets). O_W2 / O_WN2 / O_WC1T hold TRANSPOSED weights.
#define O_W1   0          // We1  [129*64] row-major
#define O_B1   8256
#define O_W2   8320       // We2^T [64*64]
#define O_B2   12416
#define O_WC1  12480      // Wc1  [64*64] row-major (atomic-fallback scalar path)
#define O_BC1  16576
#define O_WC2  16640
#define O_BC2  16704
#define O_WN1  16768      // Wn1  [128*64] row-major
#define O_BN1  24960
#define O_WN2  25024      // Wn2^T [64*64]
#define O_BN2  29120
#define O_FLAG 29184      // int: 1 = tensors bf16, 0 = f32 (written by prep, R15)
#define O_WC1T 29248      // Wc1^T [64*64] (MFMA path)

// ---- per-node layer-1 precompute (fp32):
// Y[n][0:64]=h[n]@We1[0:64] + b1 (b1 folded), Y[n][64:128]=h[n]@We1[64:128]
#define O_Y    33344                    // float [NN*128]
#define Y_END  (O_Y + NN*128)

// ---- CSR layout. N_RC holds col-only (int[NE]); ef16/tr regions unused
// (agg fused into edge kernel) but kept in the layout for ws-size gating.
#define N_OFF   Y_END                   // int off[NN+1] (padded to 50008)
#define N_CNT   (N_OFF + 50008)         // int count/cursor[NN]
#define N_RC    (N_CNT + NN)            // int col[NE] by position
#define N_AGGH  (N_RC + 2*NE)           // float [NN*64]
#define N_SUMT  (N_AGGH + NN*64)        // float [NN*3]
#define N_EF16  (N_SUMT + NN*3 + 2)     // (unused since R14)
#define N_TR    (N_EF16 + NE*32)        // (unused since R14)
#define N_TOTAL (N_TR + NE*3)           // ~39.5M words ~ 158 MB (ws gate)

// ---- atomic fallback layout ----
#define F_AGGH  Y_END
#define F_SUMT  (F_AGGH + NN*64)
#define F_CNT   (F_SUMT + NN*3)
#define F_TOTAL (F_CNT + NN)

#define OUT_COORD (NN*64)
#define OUT_V     (NN*64 + NN*3)

typedef __attribute__((ext_vector_type(8))) short bf16x8;
typedef __attribute__((ext_vector_type(4))) short bf16x4;
typedef __attribute__((ext_vector_type(4))) float f32x4;

static __device__ __forceinline__ float bf2f(const __hip_bfloat16 x) { return __bfloat162float(x); }

template<bool B16>
static __device__ __forceinline__ float ldf(const void* p, size_t i) {
    if (B16) return __bfloat162float(((const __hip_bfloat16*)p)[i]);
    else     return ((const float*)p)[i];
}
template<bool B16>
static __device__ __forceinline__ void stf(void* p, size_t i, float v) {
    if (B16) ((__hip_bfloat16*)p)[i] = __float2bfloat16(v);
    else     ((float*)p)[i] = v;
}
template<bool B16>
static __device__ __forceinline__ float4 ld4(const void* p, size_t i4) {
    if (B16) {
        uint2 u = ((const uint2*)p)[i4];
        return make_float4(__uint_as_float(u.x << 16), __uint_as_float(u.x & 0xffff0000u),
                           __uint_as_float(u.y << 16), __uint_as_float(u.y & 0xffff0000u));
    } else {
        return ((const float4*)p)[i4];
    }
}
template<bool B16>
static __device__ __forceinline__ void st4(void* p, size_t i4, float4 v) {
    if (B16) {
        stf<true>(p, 4*i4 + 0, v.x); stf<true>(p, 4*i4 + 1, v.y);
        stf<true>(p, 4*i4 + 2, v.z); stf<true>(p, 4*i4 + 3, v.w);
    } else {
        ((float4*)p)[i4] = v;
    }
}
static __device__ __forceinline__ unsigned short f2bf_bits(float x) {
    __hip_bfloat16 b = __float2bfloat16(x);
    return *reinterpret_cast<unsigned short*>(&b);
}
static __device__ __forceinline__ uint32_t pack_bf2(float lo, float hi) {
    return (uint32_t)f2bf_bits(lo) | ((uint32_t)f2bf_bits(hi) << 16);
}
static __device__ __forceinline__ short bfs(float x) {
    unsigned short u = f2bf_bits(x);
    return *reinterpret_cast<short*>(&u);
}
// runtime-dtype vector load/store (isb: 1 = tensors bf16, 0 = f32)
static __device__ __forceinline__ float4 ld4rt(const void* p, size_t i4, int isb) {
    if (isb) {
        uint2 u = ((const uint2*)p)[i4];
        return make_float4(__uint_as_float(u.x << 16), __uint_as_float(u.x & 0xffff0000u),
                           __uint_as_float(u.y << 16), __uint_as_float(u.y & 0xffff0000u));
    }
    return ((const float4*)p)[i4];
}
static __device__ __forceinline__ void st4rt(void* p, size_t i4, float4 v, int isb) {
    if (isb) {
        ((uint2*)p)[i4] = make_uint2(pack_bf2(v.x, v.y), pack_bf2(v.z, v.w));
    } else {
        ((float4*)p)[i4] = v;
    }
}

static __device__ __forceinline__ f32x4 mfma32(bf16x8 a, bf16x8 b, f32x4 c) {
    return __builtin_amdgcn_mfma_f32_16x16x32_bf16(a, b, c, 0, 0, 0);
}
static __device__ __forceinline__ f32x4 mfma16(bf16x4 a, bf16x4 b, f32x4 c) {
#if defined(__has_builtin)
#if __has_builtin(__builtin_amdgcn_mfma_f32_16x16x16bf16_1k)
    return __builtin_amdgcn_mfma_f32_16x16x16bf16_1k(a, b, c, 0, 0, 0);
#define MFMA16_DONE 1
#endif
#endif
#ifndef MFMA16_DONE
    asm volatile("v_mfma_f32_16x16x16_bf16 %0, %1, %2, %0\n\ts_nop 7\n\ts_nop 7"
                 : "+v"(c) : "v"(a), "v"(b));
    return c;
#endif
}

// ---- inline dtype sniff (R15: was its own kernel; each prep thread recomputes
// locally — 128 L1-broadcast reads. P(wrong) ~ 0.48^128.)
static __device__ __forceinline__ int sniff_isb(const uint32_t* __restrict__ w) {
    int bad = 0;
    for (int i = 0; i < 128; ++i) {
        uint32_t d = w[i];
        float a = __uint_as_float(d << 16);
        float b = __uint_as_float(d & 0xffff0000u);
        if (!(fabsf(a) <= 0.1f)) bad++;
        if (!(fabsf(b) <= 0.1f)) bad++;
    }
    return (bad == 0) ? 1 : 0;
}

// ---- weights -> fp32 in ws; W2/Wn2/WC1T transposed. Writes O_FLAG (R15).
__global__ void prep_kernel(
    const void* We1, const void* be1, const void* We2, const void* be2,
    const void* Wn1, const void* bn1, const void* Wn2, const void* bn2,
    const void* Wc1, const void* bc1, const void* Wc2, const void* bc2,
    float* __restrict__ wf)
{
    const int isb = sniff_isb((const uint32_t*)We1);
    int tid = blockIdx.x * blockDim.x + threadIdx.x;
    int stride = gridDim.x * blockDim.x;
    if (tid == 0) ((int*)wf)[O_FLAG] = isb;        // for downstream kernels
#define LD(src, i) (isb ? bf2f(((const __hip_bfloat16*)(src))[i]) : ((const float*)(src))[i])
#define CP(dst, src, n)  for (int i = tid; i < (n); i += stride) wf[(dst) + i] = LD(src, i);
#define CPT(dst, src)    for (int i = tid; i < 4096; i += stride) \
        wf[(dst) + (i & 63) * 64 + (i >> 6)] = LD(src, i);
    CP(O_W1,  We1, 129*64)  CP(O_B1,  be1, 64)
    CPT(O_W2,  We2)         CP(O_B2,  be2, 64)
    CP(O_WC1, Wc1, 64*64)   CP(O_BC1, bc1, 64)
    CPT(O_WC1T, Wc1)
    CP(O_WC2, Wc2, 64)      CP(O_BC2, bc2, 1)
    CP(O_WN1, Wn1, 128*64)  CP(O_BN1, bn1, 64)
    CPT(O_WN2, Wn2)         CP(O_BN2, bn2, 64)
#undef CP
#undef CPT
#undef LD
}

// ---- R11 (HW-verified): MFMA pre_edge — Y^T = We1^T @ h^T (+b1 on row half).
// R15: count_kernel fused in — blocks >= PRE_BLOCKS histogram edge rows and
// exit before any LDS work (block-uniform branch; no barrier hazard). In the
// small-ws fallback the launcher uses grid=PRE_BLOCKS so the branch is dead.
__global__ __launch_bounds__(256, 3) void pre_edge_kernel(
    const void* __restrict__ h, const int* __restrict__ ei, float* __restrict__ ws)
{
    if (blockIdx.x >= PRE_BLOCKS) {                // fused count (CSR path only)
        int e = (blockIdx.x - PRE_BLOCKS) * 256 + threadIdx.x;
        if (e < NE) atomicAdd((int*)ws + N_CNT + ei[e], 1);
        return;
    }

    const int isb = ((const int*)ws)[O_FLAG];
    __shared__ bf16x8 s_wh[16][64];                // We1^T frags [2t+s][lane]
    __shared__ bf16x8 s_wl[16][64];
    __shared__ __align__(16) float s_b1[64];

    const int tid = threadIdx.x;
    for (int f = tid; f < 1024; f += 256) {
        int frag = f >> 6, l = f & 63;
        int t = frag >> 1, s = frag & 1, e2 = l & 15, g2 = l >> 4;
        const float* p = ws + O_W1 + (size_t)((t >= 4 ? 64 : 0) + 32*s + 8*g2) * 64
                         + 16*(t & 3) + e2;
        bf16x8 rh, rl;
        #pragma unroll
        for (int j = 0; j < 8; ++j) {
            float w = p[j * 64];
            unsigned short hb = f2bf_bits(w);
            rh[j] = (short)hb;
            rl[j] = bfs(w - __uint_as_float((uint32_t)hb << 16));
        }
        s_wh[frag][l] = rh; s_wl[frag][l] = rl;
    }
    for (int i = tid; i < 64; i += 256) s_b1[i] = ws[O_B1 + i];
    __syncthreads();

    const int lane = tid & 63, e = lane & 15, g = lane >> 4;
    const int c = blockIdx.x * 4 + (tid >> 6);
    if (c >= NN / 16) return;
    asm volatile("" ::: "memory");                 // keep LDS reads below (R8 lesson)
    const int n = c * 16 + e;

    bf16x8 bhi[2], blo[2];
    #pragma unroll
    for (int s = 0; s < 2; ++s) {
        float4 a0 = ld4rt(h, (size_t)n * 16 + 8*s + 2*g, isb);
        float4 a1 = ld4rt(h, (size_t)n * 16 + 8*s + 2*g + 1, isb);
        float a[8] = {a0.x, a0.y, a0.z, a0.w, a1.x, a1.y, a1.z, a1.w};
        bf16x8 h8, l8;
        #pragma unroll
        for (int j = 0; j < 8; ++j) {
            unsigned short hb = f2bf_bits(a[j]);
            h8[j] = (short)hb;
            l8[j] = bfs(a[j] - __uint_as_float((uint32_t)hb << 16));
        }
        bhi[s] = h8; blo[s] = l8;
    }

    #pragma unroll
    for (int t = 0; t < 8; ++t) {
        f32x4 d;
        if (t < 4) d = *(const f32x4*)&s_b1[16*t + 4*g];
        else       d = (f32x4){0.0f, 0.0f, 0.0f, 0.0f};
        #pragma unroll
        for (int s = 0; s < 2; ++s) {
            bf16x8 wh = s_wh[2*t + s][lane];
            bf16x8 wl = s_wl[2*t + s][lane];
            d = mfma32(wh, bhi[s], d);
            d = mfma32(wh, blo[s], d);
            d = mfma32(wl, bhi[s], d);
        }
        *(float4*)(ws + O_Y + (size_t)n * 128 + 16*t + 4*g) =
            make_float4(d[0], d[1], d[2], d[3]);
    }
}

// ---- edge MLP scalar core (atomic-fallback only) ----
template<bool B16>
static __device__ __forceinline__ void edge_mlp(
    const void* __restrict__ coord, const float* __restrict__ wf,
    int row, int col,
    float4 efbuf[16], float& gate, float& cdx, float& cdy, float& cdz)
{
    cdx = ldf<B16>(coord, 3*row + 0) - ldf<B16>(coord, 3*col + 0);
    cdy = ldf<B16>(coord, 3*row + 1) - ldf<B16>(coord, 3*col + 1);
    cdz = ldf<B16>(coord, 3*row + 2) - ldf<B16>(coord, 3*col + 2);
    float radial = cdx*cdx + cdy*cdy + cdz*cdz;

    const float4* yrv = (const float4*)(wf + O_Y + (size_t)row * 128);
    const float4* ycv = (const float4*)(wf + O_Y + (size_t)col * 128 + 64);

    float acc[64];
    #pragma unroll
    for (int q = 0; q < 16; ++q) {
        float4 a = yrv[q];
        float4 b = ycv[q];
        const float* wr = wf + O_W1 + 128 * 64 + q * 4;
        acc[4*q+0] = fmaxf(fmaf(radial, wr[0], a.x + b.x), 0.0f);
        acc[4*q+1] = fmaxf(fmaf(radial, wr[1], a.y + b.y), 0.0f);
        acc[4*q+2] = fmaxf(fmaf(radial, wr[2], a.z + b.z), 0.0f);
        acc[4*q+3] = fmaxf(fmaf(radial, wr[3], a.w + b.w), 0.0f);
    }

    #pragma unroll
    for (int j0 = 0; j0 < 16; ++j0) {
        float c[4];
        #pragma unroll
        for (int u = 0; u < 4; ++u) {
            int j = j0 * 4 + u;
            float t = wf[O_B2 + j];
            const float* w2t = wf + O_W2 + j * 64;
            #pragma unroll
            for (int k = 0; k < 64; ++k) t = fmaf(acc[k], w2t[k], t);
            c[u] = fmaxf(t, 0.0f);
        }
        efbuf[j0] = make_float4(c[0], c[1], c[2], c[3]);
    }

    float hid[64];
    #pragma unroll
    for (int j = 0; j < 64; ++j) hid[j] = wf[O_BC1 + j];
    #pragma unroll
    for (int j0 = 0; j0 < 16; ++j0) {
        float4 ef4 = efbuf[j0];
        const float* w0 = wf + O_WC1 + (j0 * 4 + 0) * 64;
        const float* w1 = wf + O_WC1 + (j0 * 4 + 1) * 64;
        const float* w2 = wf + O_WC1 + (j0 * 4 + 2) * 64;
        const float* w3 = wf + O_WC1 + (j0 * 4 + 3) * 64;
        #pragma unroll
        for (int jj = 0; jj < 64; ++jj) hid[jj] = fmaf(ef4.x, w0[jj], hid[jj]);
        #pragma unroll
        for (int jj = 0; jj < 64; ++jj) hid[jj] = fmaf(ef4.y, w1[jj], hid[jj]);
        #pragma unroll
        for (int jj = 0; jj < 64; ++jj) hid[jj] = fmaf(ef4.z, w2[jj], hid[jj]);
        #pragma unroll
        for (int jj = 0; jj < 64; ++jj) hid[jj] = fmaf(ef4.w, w3[jj], hid[jj]);
    }

    float g0 = wf[O_BC2], g1 = 0.0f, g2 = 0.0f, g3 = 0.0f;
    #pragma unroll
    for (int j = 0; j < 64; j += 4) {
        g0 = fmaf(fmaxf(hid[j + 0], 0.0f), wf[O_WC2 + j + 0], g0);
        g1 = fmaf(fmaxf(hid[j + 1], 0.0f), wf[O_WC2 + j + 1], g1);
        g2 = fmaf(fmaxf(hid[j + 2], 0.0f), wf[O_WC2 + j + 2], g2);
        g3 = fmaf(fmaxf(hid[j + 3], 0.0f), wf[O_WC2 + j + 3], g3);
    }
    gate = (g0 + g1) + (g2 + g3);
}

// ============ CSR path ============
// R12 (HW-verified): 4 elements/thread, 13 iterations.
__global__ __launch_bounds__(1024) void scan_kernel(float* __restrict__ ws) {
    int* cnt = (int*)ws + N_CNT;
    int* off = (int*)ws + N_OFF;
    __shared__ int wsum[16];
    __shared__ int carry_s;
    int tid = threadIdx.x, lane = tid & 63, wid = tid >> 6;
    if (tid == 0) carry_s = 0;
    __syncthreads();
    for (int base = 0; base < NN; base += 4096) {
        int i0 = base + tid * 4;
        int a0 = (i0 + 0 < NN) ? cnt[i0 + 0] : 0;
        int a1 = (i0 + 1 < NN) ? cnt[i0 + 1] : 0;
        int a2 = (i0 + 2 < NN) ? cnt[i0 + 2] : 0;
        int a3 = (i0 + 3 < NN) ? cnt[i0 + 3] : 0;
        int tsum = ((a0 + a1) + (a2 + a3));
        int v = tsum;
        #pragma unroll
        for (int s = 1; s < 64; s <<= 1) { int t = __shfl_up(v, s, 64); if (lane >= s) v += t; }
        if (lane == 63) wsum[wid] = v;
        __syncthreads();
        if (wid == 0) {
            int w = (lane < 16) ? wsum[lane] : 0;
            #pragma unroll
            for (int s = 1; s < 16; s <<= 1) { int t = __shfl_up(w, s, 64); if (lane >= s) w += t; }
            if (lane < 16) wsum[lane] = w;
        }
        __syncthreads();
        int waveback = (wid > 0) ? wsum[wid - 1] : 0;
        int excl = carry_s + waveback + (v - tsum);
        if (i0 + 0 < NN) { off[i0 + 0] = excl; cnt[i0 + 0] = excl; }
        excl += a0;
        if (i0 + 1 < NN) { off[i0 + 1] = excl; cnt[i0 + 1] = excl; }
        excl += a1;
        if (i0 + 2 < NN) { off[i0 + 2] = excl; cnt[i0 + 2] = excl; }
        excl += a2;
        if (i0 + 3 < NN) { off[i0 + 3] = excl; cnt[i0 + 3] = excl; }
        __syncthreads();
        if (tid == 0) carry_s += wsum[15];
        __syncthreads();
    }
    if (threadIdx.x == 0) off[NN] = carry_s;
}

// store col only (4B) — row is implicit in the node-based edge kernel.
__global__ __launch_bounds__(256) void scatter_kernel(
    const int* __restrict__ ei, float* __restrict__ ws)
{
    int e = blockIdx.x * 256 + threadIdx.x;
    if (e >= NE) return;
    int row = ei[e];
    int col = ei[NE + e];
    int pos = atomicAdd((int*)ws + N_CNT + row, 1);
    ((int*)ws + N_RC)[pos] = col;
}

// ---- R12 (HW-verified, 110.9us): node-based MFMA edge kernel, FUSED agg.
// Chunk-loop anti-LICM fence + full scalarization; bounds (256,3) — R13/R14
// bracketed this as the local optimum (6 waves spills; 4 waves no change).
#define SPLIT1(H, L, IDX, VAL, WI) { \
    float _v = fmaxf(fmaf(radial, s_w1r[WI], (VAL)), 0.0f); \
    unsigned short _hb = f2bf_bits(_v); \
    H[IDX] = (short)_hb; \
    L[IDX] = bfs(_v - __uint_as_float((uint32_t)_hb << 16)); }
#define SPLIT8(H, L, WOFF, V0,V1,V2,V3,V4,V5,V6,V7) \
    SPLIT1(H,L,0,V0,(WOFF)+0) SPLIT1(H,L,1,V1,(WOFF)+1) \
    SPLIT1(H,L,2,V2,(WOFF)+2) SPLIT1(H,L,3,V3,(WOFF)+3) \
    SPLIT1(H,L,4,V4,(WOFF)+4) SPLIT1(H,L,5,V5,(WOFF)+5) \
    SPLIT1(H,L,6,V6,(WOFF)+6) SPLIT1(H,L,7,V7,(WOFF)+7)
#define PHASEB(D, T) { \
    bf16x8 wh0 = s_wbh[2*(T)+0][lane], wh1 = s_wbh[2*(T)+1][lane]; \
    bf16x8 wl0 = s_wbl[2*(T)+0][lane], wl1 = s_wbl[2*(T)+1][lane]; \
    D = mfma32(wh0, ahi0, D); D = mfma32(wh1, ahi1, D); \
    D = mfma32(wh0, alo0, D); D = mfma32(wh1, alo1, D); \
    D = mfma32(wl0, ahi0, D); D = mfma32(wl1, ahi1, D); }
#define EFBLK(D, BQ, A0,A1,A2,A3) { \
    float _e0 = fmaxf(D[0], 0.0f) * vmask; \
    float _e1 = fmaxf(D[1], 0.0f) * vmask; \
    float _e2 = fmaxf(D[2], 0.0f) * vmask; \
    float _e3 = fmaxf(D[3], 0.0f) * vmask; \
    BQ[0] = (short)f2bf_bits(_e0); BQ[1] = (short)f2bf_bits(_e1); \
    BQ[2] = (short)f2bf_bits(_e2); BQ[3] = (short)f2bf_bits(_e3); \
    A0 += _e0; A1 += _e1; A2 += _e2; A3 += _e3; }
#define PHASEC(D, U) { \
    D = mfma16(s_wc[4*(U)+0][lane], bq0, D); \
    D = mfma16(s_wc[4*(U)+1][lane], bq1, D); \
    D = mfma16(s_wc[4*(U)+2][lane], bq2, D); \
    D = mfma16(s_wc[4*(U)+3][lane], bq3, D); }
#define GATEU(D, U) { \
    gp = fmaf(fmaxf(D[0], 0.0f), s_wc2[16*(U) + 4*g + 0], gp); \
    gp = fmaf(fmaxf(D[1], 0.0f), s_wc2[16*(U) + 4*g + 1], gp); \
    gp = fmaf(fmaxf(D[2], 0.0f), s_wc2[16*(U) + 4*g + 2], gp); \
    gp = fmaf(fmaxf(D[3], 0.0f), s_wc2[16*(U) + 4*g + 3], gp); }
#define RED16(M) \
    ag00 += __shfl_xor(ag00,M,64); ag01 += __shfl_xor(ag01,M,64); \
    ag02 += __shfl_xor(ag02,M,64); ag03 += __shfl_xor(ag03,M,64); \
    ag10 += __shfl_xor(ag10,M,64); ag11 += __shfl_xor(ag11,M,64); \
    ag12 += __shfl_xor(ag12,M,64); ag13 += __shfl_xor(ag13,M,64); \
    ag20 += __shfl_xor(ag20,M,64); ag21 += __shfl_xor(ag21,M,64); \
    ag22 += __shfl_xor(ag22,M,64); ag23 += __shfl_xor(ag23,M,64); \
    ag30 += __shfl_xor(ag30,M,64); ag31 += __shfl_xor(ag31,M,64); \
    ag32 += __shfl_xor(ag32,M,64); ag33 += __shfl_xor(ag33,M,64);

__global__ __launch_bounds__(256, 3) void edge_csr_kernel(
    const void* __restrict__ coord, float* __restrict__ ws)
{
    const int isb = ((const int*)ws)[O_FLAG];

    __shared__ bf16x8 s_wbh[8][64];                // We2^T hi frags [2t+s][lane], 8KB
    __shared__ bf16x8 s_wbl[8][64];                // We2^T lo frags, 8KB
    __shared__ bf16x4 s_wc[16][64];                // Wc1^T frags [4u+t][lane], 8KB
    __shared__ __align__(16) float s_b2[64];
    __shared__ __align__(16) float s_bc1[64];
    __shared__ __align__(16) float s_wc2[64];
    __shared__ float s_w1r[64];
    __shared__ float s_bc2v;

    const int tid = threadIdx.x;
    for (int f = tid; f < 512; f += 256) {         // We2^T hi/lo fill
        int frag = f >> 6, l = f & 63;
        int t = frag >> 1, s = frag & 1, e2 = l & 15, g2 = l >> 4;
        const float* p = ws + O_W2 + (16*t + e2)*64 + 32*s + 8*g2;
        bf16x8 rh, rl;
        #pragma unroll
        for (int j = 0; j < 8; ++j) {
            float w = p[j];
            unsigned short hb = f2bf_bits(w);
            rh[j] = (short)hb;
            float hf = __uint_as_float((uint32_t)hb << 16);
            rl[j] = bfs(w - hf);
        }
        s_wbh[frag][l] = rh;
        s_wbl[frag][l] = rl;
    }
    for (int f = tid; f < 1024; f += 256) {        // Wc1^T fill (hi only)
        int frag = f >> 6, l = f & 63;
        int u = frag >> 2, t = frag & 3, e2 = l & 15, g2 = l >> 4;
        const float* p = ws + O_WC1T + (16*u + e2)*64 + 16*t + 4*g2;
        bf16x4 r;
        #pragma unroll
        for (int j = 0; j < 4; ++j) r[j] = bfs(p[j]);
        s_wc[frag][l] = r;
    }
    for (int i = tid; i < 64; i += 256) {
        s_b2[i]  = ws[O_B2 + i];
        s_bc1[i] = ws[O_BC1 + i];
        s_wc2[i] = ws[O_WC2 + i];
        s_w1r[i] = ws[O_W1 + 128*64 + i];          // radial row of We1
    }
    if (tid == 0) s_bc2v = ws[O_BC2];
    __syncthreads();

    const int lane = threadIdx.x & 63;
    const int e = lane & 15, g = lane >> 4;
    const int wid = blockIdx.x * 4 + (int)(threadIdx.x >> 6);
    const int nw = 4096;                           // grid is exactly 1024 blocks
    const int* off = (const int*)ws + N_OFF;
    const int* colA = (const int*)ws + N_RC;
    const float* cf = (const float*)coord;
    const __hip_bfloat16* cbh = (const __hip_bfloat16*)coord;

    for (int n = wid; n < NN; n += nw) {
        const int s0 = off[n], s1 = off[n + 1];

        // node (row) coords — wave-uniform
        float crx, cry, crz;
        if (isb) {
            crx = bf2f(cbh[3*n+0]); cry = bf2f(cbh[3*n+1]); crz = bf2f(cbh[3*n+2]);
        } else {
            crx = cf[3*n+0]; cry = cf[3*n+1]; crz = cf[3*n+2];
        }
        // row-half Y (k = 32s + 8g + j) — uniform across e-lanes; SCALARIZED
        float y00, y01, y02, y03, y04, y05, y06, y07;
        float y10, y11, y12, y13, y14, y15, y16, y17;
        {
            const float4* yr4 = (const float4*)(ws + O_Y + (size_t)n * 128 + 8*g);
            float4 ra = yr4[0], rb = yr4[1];
            y00=ra.x; y01=ra.y; y02=ra.z; y03=ra.w;
            y04=rb.x; y05=rb.y; y06=rb.z; y07=rb.w;
        }
        {
            const float4* yr4 = (const float4*)(ws + O_Y + (size_t)n * 128 + 32 + 8*g);
            float4 ra = yr4[0], rb = yr4[1];
            y10=ra.x; y11=ra.y; y12=ra.z; y13=ra.w;
            y14=rb.x; y15=rb.y; y16=rb.z; y17=rb.w;
        }

        // SCALARIZED accumulators (rule #20 hard-proofing)
        float ag00=0.f, ag01=0.f, ag02=0.f, ag03=0.f;
        float ag10=0.f, ag11=0.f, ag12=0.f, ag13=0.f;
        float ag20=0.f, ag21=0.f, ag22=0.f, ag23=0.f;
        float ag30=0.f, ag31=0.f, ag32=0.f, ag33=0.f;
        float tx = 0.0f, ty = 0.0f, tz = 0.0f;

        for (int base = s0; base < s1; base += 16) {
            // anti-LICM fence INSIDE the weight-consuming loop (R12-proven
            // placement; a node-level fence lets LICM hoist the LDS weight
            // reads out of this loop -> spill -> GB-scale scratch traffic).
            asm volatile("" ::: "memory");

            const int cnt = s1 - base;             // >= 1 here
            const bool valid = e < cnt;
            const int col = colA[base + (valid ? e : 0)];

            float ccx, ccy, ccz;
            if (isb) {
                ccx = bf2f(cbh[3*col+0]); ccy = bf2f(cbh[3*col+1]); ccz = bf2f(cbh[3*col+2]);
            } else {
                ccx = cf[3*col+0]; ccy = cf[3*col+1]; ccz = cf[3*col+2];
            }
            float cdx = crx - ccx, cdy = cry - ccy, cdz = crz - ccz;
            float radial = cdx*cdx + cdy*cdy + cdz*cdz;

            // acc (k = 32s + 8g + j) in fp32, split hi/lo bf16 — SCALARIZED
            const float* Yc = ws + O_Y + (size_t)col * 128 + 64;
            bf16x8 ahi0, alo0, ahi1, alo1;
            {
                const float4* yc4 = (const float4*)(Yc + 8*g);
                float4 ca = yc4[0], cb4 = yc4[1];
                SPLIT8(ahi0, alo0, 8*g,
                       y00+ca.x, y01+ca.y, y02+ca.z, y03+ca.w,
                       y04+cb4.x, y05+cb4.y, y06+cb4.z, y07+cb4.w)
            }
            {
                const float4* yc4 = (const float4*)(Yc + 32 + 8*g);
                float4 ca = yc4[0], cb4 = yc4[1];
                SPLIT8(ahi1, alo1, 32 + 8*g,
                       y10+ca.x, y11+ca.y, y12+ca.z, y13+ca.w,
                       y14+cb4.x, y15+cb4.y, y16+cb4.z, y17+cb4.w)
            }

            // phase B: D1[ef][edge], C-init = b2; 3-product hi/lo
            f32x4 d10 = *(const f32x4*)&s_b2[ 0 + 4*g];
            f32x4 d11 = *(const f32x4*)&s_b2[16 + 4*g];
            f32x4 d12 = *(const f32x4*)&s_b2[32 + 4*g];
            f32x4 d13 = *(const f32x4*)&s_b2[48 + 4*g];
            PHASEB(d10, 0) PHASEB(d11, 1) PHASEB(d12, 2) PHASEB(d13, 3)

            // relu (fp32) + validity mask; bq = bf16(ef) for the gate path
            const float vmask = valid ? 1.0f : 0.0f;
            bf16x4 bq0, bq1, bq2, bq3;
            EFBLK(d10, bq0, ag00, ag01, ag02, ag03)
            EFBLK(d11, bq1, ag10, ag11, ag12, ag13)
            EFBLK(d12, bq2, ag20, ag21, ag22, ag23)
            EFBLK(d13, bq3, ag30, ag31, ag32, ag33)

            // phase C: D2[hid][edge] = Wc1^T @ ef^T, C-init = bc1
            f32x4 d20 = *(const f32x4*)&s_bc1[ 0 + 4*g];
            f32x4 d21 = *(const f32x4*)&s_bc1[16 + 4*g];
            f32x4 d22 = *(const f32x4*)&s_bc1[32 + 4*g];
            f32x4 d23 = *(const f32x4*)&s_bc1[48 + 4*g];
            PHASEC(d20, 0) PHASEC(d21, 1) PHASEC(d22, 2) PHASEC(d23, 3)

            // gate = bc2 + sum_h relu(hid[h]) * Wc2[h]; reduce over 4 g-groups
            float gp = 0.0f;
            GATEU(d20, 0) GATEU(d21, 1) GATEU(d22, 2) GATEU(d23, 3)
            gp += __shfl_xor(gp, 16, 64);
            gp += __shfl_xor(gp, 32, 64);
            float gate = gp + s_bc2v;

            if (valid && g == 0) {
                tx += fminf(fmaxf(cdx * gate, -100.0f), 100.0f);
                ty += fminf(fmaxf(cdy * gate, -100.0f), 100.0f);
                tz += fminf(fmaxf(cdz * gate, -100.0f), 100.0f);
            }
        }

        // cross-edge reduce of agg (over e-lanes, within each g-group)
        RED16(1) RED16(2) RED16(4) RED16(8)

        // write agg row: lane (e=t, g) stores features 16t+4g+{0..3}
        float* aggw = ws + N_AGGH + (size_t)n * 64;
        if (e == 0)      *(float4*)(aggw + 0  + 4*g) = make_float4(ag00, ag01, ag02, ag03);
        else if (e == 1) *(float4*)(aggw + 16 + 4*g) = make_float4(ag10, ag11, ag12, ag13);
        else if (e == 2) *(float4*)(aggw + 32 + 4*g) = make_float4(ag20, ag21, ag22, ag23);
        else if (e == 3) *(float4*)(aggw + 48 + 4*g) = make_float4(ag30, ag31, ag32, ag33);

        // cross-edge reduce of trans (g==0 lanes hold partials)
        tx += __shfl_xor(tx, 1, 64); ty += __shfl_xor(ty, 1, 64); tz += __shfl_xor(tz, 1, 64);
        tx += __shfl_xor(tx, 2, 64); ty += __shfl_xor(ty, 2, 64); tz += __shfl_xor(tz, 2, 64);
        tx += __shfl_xor(tx, 4, 64); ty += __shfl_xor(ty, 4, 64); tz += __shfl_xor(tz, 4, 64);
        tx += __shfl_xor(tx, 8, 64); ty += __shfl_xor(ty, 8, 64); tz += __shfl_xor(tz, 8, 64);
        if (lane == 0) {
            ws[N_SUMT + 3*(size_t)n + 0] = tx;
            ws[N_SUMT + 3*(size_t)n + 1] = ty;
            ws[N_SUMT + 3*(size_t)n + 2] = tz;
        }
    }
}
#undef SPLIT1
#undef SPLIT8
#undef PHASEB
#undef EFBLK
#undef PHASEC
#undef GATEU
#undef RED16

// ---- scalar node core (atomic fallback only) ----
template<bool B16>
static __device__ __forceinline__ void node_core(
    const void* __restrict__ h, const void* __restrict__ coord,
    const void* __restrict__ vel, const float* __restrict__ ws,
    const float* __restrict__ agg, const float* __restrict__ sumt, float cntf,
    void* __restrict__ out, int n)
{
    float inv = (cntf > 0.0f) ? (1.0f / fmaxf(cntf, 1.0f)) : 0.0f;
    #pragma unroll
    for (int i = 0; i < 3; ++i) {
        float aggc = sumt[3*n + i] * inv;
        float v = ldf<B16>(vel, 3*n + i) + aggc * 0.125f;
        float cn = ldf<B16>(coord, 3*n + i) + v * 0.125f;
        stf<B16>(out, OUT_COORD + 3*n + i, cn);
        stf<B16>(out, OUT_V + 3*n + i, v);
    }

    float acc[64];
    #pragma unroll
    for (int j = 0; j < 64; ++j) acc[j] = ws[O_BN1 + j];

    #pragma unroll 4
    for (int q = 0; q < 16; ++q) {
        float4 a = ld4<B16>(h, (size_t)n * 16 + q);
        const float* w = ws + O_WN1 + (q * 4) * 64;
        #pragma unroll
        for (int j = 0; j < 64; ++j) acc[j] = fmaf(a.x, w[j], acc[j]);
        #pragma unroll
        for (int j = 0; j < 64; ++j) acc[j] = fmaf(a.y, w[64 + j], acc[j]);
        #pragma unroll
        for (int j = 0; j < 64; ++j) acc[j] = fmaf(a.z, w[128 + j], acc[j]);
        #pragma unroll
        for (int j = 0; j < 64; ++j) acc[j] = fmaf(a.w, w[192 + j], acc[j]);
    }
    const float4* agv = (const float4*)(agg + (size_t)n * 64);
    #pragma unroll 4
    for (int q = 0; q < 16; ++q) {
        float4 a = agv[q];
        const float* w = ws + O_WN1 + (64 + q * 4) * 64;
        #pragma unroll
        for (int j = 0; j < 64; ++j) acc[j] = fmaf(a.x, w[j], acc[j]);
        #pragma unroll
        for (int j = 0; j < 64; ++j) acc[j] = fmaf(a.y, w[64 + j], acc[j]);
        #pragma unroll
        for (int j = 0; j < 64; ++j) acc[j] = fmaf(a.z, w[128 + j], acc[j]);
        #pragma unroll
        for (int j = 0; j < 64; ++j) acc[j] = fmaf(a.w, w[192 + j], acc[j]);
    }
    #pragma unroll
    for (int j = 0; j < 64; ++j) acc[j] = fmaxf(acc[j], 0.0f);

    float4 ob[16];
    #pragma unroll
    for (int j0 = 0; j0 < 16; ++j0) {
        float4 hres = ld4<B16>(h, (size_t)n * 16 + j0);
        float c[4];
        #pragma unroll
        for (int u = 0; u < 4; ++u) {
            int j = j0 * 4 + u;
            float t = ws[O_BN2 + j];
            const float* w = ws + O_WN2 + j * 64;
            #pragma unroll
            for (int k = 0; k < 64; ++k) t = fmaf(acc[k], w[k], t);
            c[u] = t;
        }
        ob[j0] = make_float4(hres.x + c[0], hres.y + c[1], hres.z + c[2], hres.w + c[3]);
    }
    #pragma unroll
    for (int j0 = 0; j0 < 16; ++j0) st4<B16>(out, (size_t)n * 16 + j0, ob[j0]);
}

// ---- R11 (HW-verified): MFMA node kernel (CSR path, both dtypes).
__global__ __launch_bounds__(256, 3) void node_kernel_csr(
    const void* __restrict__ h, const void* __restrict__ coord,
    const void* __restrict__ vel, const float* __restrict__ ws,
    void* __restrict__ out)
{
    const int isb = ((const int*)ws)[O_FLAG];

    __shared__ bf16x8 s_w1h[16][64];               // Wn1^T frags [4t+s][lane], 16KB
    __shared__ bf16x8 s_w1l[16][64];               // 16KB
    __shared__ bf16x4 s_w2h[16][64];               // Wn2^T frags [4u+t][lane], 8KB
    __shared__ bf16x4 s_w2l[16][64];               // 8KB
    __shared__ __align__(16) float s_bn1[64];
    __shared__ __align__(16) float s_bn2[64];

    const int tid = threadIdx.x;
    for (int f = tid; f < 1024; f += 256) {        // Wn1^T hi/lo fill
        int frag = f >> 6, l = f & 63;
        int t = frag >> 2, s = frag & 3, e2 = l & 15, g2 = l >> 4;
        const float* p = ws + O_WN1 + (size_t)(32*s + 8*g2) * 64 + 16*t + e2;
        bf16x8 rh, rl;
        #pragma unroll
        for (int j = 0; j < 8; ++j) {
            float w = p[j * 64];
            unsigned short hb = f2bf_bits(w);
            rh[j] = (short)hb;
            rl[j] = bfs(w - __uint_as_float((uint32_t)hb << 16));
        }
        s_w1h[frag][l] = rh; s_w1l[frag][l] = rl;
    }
    for (int f = tid; f < 1024; f += 256) {        // Wn2^T hi/lo fill
        int frag = f >> 6, l = f & 63;
        int u = frag >> 2, t = frag & 3, e2 = l & 15, g2 = l >> 4;
        const float* p = ws + O_WN2 + (16*u + e2) * 64 + 16*t + 4*g2;
        bf16x4 rh, rl;
        #pragma unroll
        for (int j = 0; j < 4; ++j) {
            float w = p[j];
            unsigned short hb = f2bf_bits(w);
            rh[j] = (short)hb;
            rl[j] = bfs(w - __uint_as_float((uint32_t)hb << 16));
        }
        s_w2h[frag][l] = rh; s_w2l[frag][l] = rl;
    }
    for (int i = tid; i < 64; i += 256) { s_bn1[i] = ws[O_BN1 + i]; s_bn2[i] = ws[O_BN2 + i]; }
    __syncthreads();

    const int lane = tid & 63, e = lane & 15, g = lane >> 4;
    const int c = blockIdx.x * 4 + (tid >> 6);
    if (c >= NN / 16) return;
    asm volatile("" ::: "memory");                 // anti-LICM
    const int n = c * 16 + e;

    // coord / vel epilogue on g==0 lanes
    if (g == 0) {
        const int* off = (const int*)ws + N_OFF;
        float cntf = (float)(off[n + 1] - off[n]);
        float inv = (cntf > 0.0f) ? (1.0f / fmaxf(cntf, 1.0f)) : 0.0f;
        #pragma unroll
        for (int i = 0; i < 3; ++i) {
            float aggc = ws[N_SUMT + 3*n + i] * inv;
            float vv, cc;
            if (isb) {
                vv = bf2f(((const __hip_bfloat16*)vel)[3*n + i]);
                cc = bf2f(((const __hip_bfloat16*)coord)[3*n + i]);
            } else {
                vv = ((const float*)vel)[3*n + i];
                cc = ((const float*)coord)[3*n + i];
            }
            float v = vv + aggc * 0.125f;
            float cn = cc + v * 0.125f;
            if (isb) {
                ((__hip_bfloat16*)out)[OUT_COORD + 3*n + i] = __float2bfloat16(cn);
                ((__hip_bfloat16*)out)[OUT_V + 3*n + i] = __float2bfloat16(v);
            } else {
                ((float*)out)[OUT_COORD + 3*n + i] = cn;
                ((float*)out)[OUT_V + 3*n + i] = v;
            }
        }
    }

    // B-op: K=128 = h[0:64] ++ agg[0:64], hi/lo split (k = 32s + 8g + j)
    bf16x8 bhi[4], blo[4];
    #pragma unroll
    for (int s = 0; s < 4; ++s) {
        float a[8];
        if (s < 2) {
            float4 a0 = ld4rt(h, (size_t)n * 16 + 8*s + 2*g, isb);
            float4 a1 = ld4rt(h, (size_t)n * 16 + 8*s + 2*g + 1, isb);
            a[0]=a0.x; a[1]=a0.y; a[2]=a0.z; a[3]=a0.w;
            a[4]=a1.x; a[5]=a1.y; a[6]=a1.z; a[7]=a1.w;
        } else {
            const float4* ag = (const float4*)(ws + N_AGGH + (size_t)n * 64);
            float4 a0 = ag[8*(s-2) + 2*g];
            float4 a1 = ag[8*(s-2) + 2*g + 1];
            a[0]=a0.x; a[1]=a0.y; a[2]=a0.z; a[3]=a0.w;
            a[4]=a1.x; a[5]=a1.y; a[6]=a1.z; a[7]=a1.w;
        }
        bf16x8 h8, l8;
        #pragma unroll
        for (int j = 0; j < 8; ++j) {
            unsigned short hb = f2bf_bits(a[j]);
            h8[j] = (short)hb;
            l8[j] = bfs(a[j] - __uint_as_float((uint32_t)hb << 16));
        }
        bhi[s] = h8; blo[s] = l8;
    }

    // N1 (3-product hi/lo)
    f32x4 d1[4];
    #pragma unroll
    for (int t = 0; t < 4; ++t) d1[t] = *(const f32x4*)&s_bn1[16*t + 4*g];
    #pragma unroll
    for (int t = 0; t < 4; ++t) {
        #pragma unroll
        for (int s = 0; s < 4; ++s) {
            bf16x8 wh = s_w1h[4*t + s][lane];
            bf16x8 wl = s_w1l[4*t + s][lane];
            d1[t] = mfma32(wh, bhi[s], d1[t]);
            d1[t] = mfma32(wh, blo[s], d1[t]);
            d1[t] = mfma32(wl, bhi[s], d1[t]);
        }
    }

    // relu -> hi/lo fragments (features 16t+4g+{0..3})
    bf16x4 rhi[4], rlo[4];
    #pragma unroll
    for (int t = 0; t < 4; ++t) {
        #pragma unroll
        for (int j = 0; j < 4; ++j) {
            float v = fmaxf(d1[t][j], 0.0f);
            unsigned short hb = f2bf_bits(v);
            rhi[t][j] = (short)hb;
            rlo[t][j] = bfs(v - __uint_as_float((uint32_t)hb << 16));
        }
    }

    // N2 (3-product)
    f32x4 d2[4];
    #pragma unroll
    for (int u = 0; u < 4; ++u) d2[u] = *(const f32x4*)&s_bn2[16*u + 4*g];
    #pragma unroll
    for (int u = 0; u < 4; ++u) {
        #pragma unroll
        for (int t = 0; t < 4; ++t) {
            bf16x4 wh = s_w2h[4*u + t][lane];
            bf16x4 wl = s_w2l[4*u + t][lane];
            d2[u] = mfma16(wh, rhi[t], d2[u]);
            d2[u] = mfma16(wh, rlo[t], d2[u]);
            d2[u] = mfma16(wl, rhi[t], d2[u]);
        }
    }

    // residual + store (features 16u+4g+{0..3} -> float4 at h[n][16u+4g])
    #pragma unroll
    for (int u = 0; u < 4; ++u) {
        float4 hres = ld4rt(h, (size_t)n * 16 + 4*u + g, isb);
        float4 o = make_float4(hres.x + d2[u][0], hres.y + d2[u][1],
                               hres.z + d2[u][2], hres.w + d2[u][3]);
        st4rt(out, (size_t)n * 16 + 4*u + g, o, isb);
    }
}

// ============ atomic fallback (small ws) ============
template<bool B16>
static __device__ __forceinline__ void edge_atomic_core(
    const void* __restrict__ coord, const int* __restrict__ ei,
    float* __restrict__ ws, int e)
{
    int row = ei[e];
    int col = ei[NE + e];
    float gate, cdx, cdy, cdz;
    float4 efbuf[16];
    edge_mlp<B16>(coord, ws, row, col, efbuf, gate, cdx, cdy, cdz);

    float* ah = ws + F_AGGH + (size_t)row * 64;
    #pragma unroll
    for (int q = 0; q < 16; ++q) {
        unsafeAtomicAdd(&ah[4*q + 0], efbuf[q].x);
        unsafeAtomicAdd(&ah[4*q + 1], efbuf[q].y);
        unsafeAtomicAdd(&ah[4*q + 2], efbuf[q].z);
        unsafeAtomicAdd(&ah[4*q + 3], efbuf[q].w);
    }
    unsafeAtomicAdd(&ws[F_SUMT + 3*row + 0], fminf(fmaxf(cdx * gate, -100.0f), 100.0f));
    unsafeAtomicAdd(&ws[F_SUMT + 3*row + 1], fminf(fmaxf(cdy * gate, -100.0f), 100.0f));
    unsafeAtomicAdd(&ws[F_SUMT + 3*row + 2], fminf(fmaxf(cdz * gate, -100.0f), 100.0f));
    unsafeAtomicAdd(&ws[F_CNT + row], 1.0f);
}

__global__ __launch_bounds__(256, 2) void edge_atomic_kernel(
    const void* __restrict__ coord, const int* __restrict__ ei,
    float* __restrict__ ws)
{
    int e = blockIdx.x * 256 + threadIdx.x;
    if (e >= NE) return;
    if (((const int*)ws)[O_FLAG]) edge_atomic_core<true>(coord, ei, ws, e);
    else                          edge_atomic_core<false>(coord, ei, ws, e);
}

__global__ __launch_bounds__(256, 2) void node_kernel_atomic(
    const void* __restrict__ h, const void* __restrict__ coord,
    const void* __restrict__ vel, const float* __restrict__ ws,
    void* __restrict__ out)
{
    int n = blockIdx.x * 256 + threadIdx.x;
    if (n >= NN) return;
    float cntf = ws[F_CNT + n];
    if (((const int*)ws)[O_FLAG])
        node_core<true>(h, coord, vel, ws, ws + F_AGGH, ws + F_SUMT, cntf, out, n);
    else
        node_core<false>(h, coord, vel, ws, ws + F_AGGH, ws + F_SUMT, cntf, out, n);
}

extern "C" void kernel_launch(void* const* d_in, const int* in_sizes, int n_in,
                              void* d_out, int out_size, void* d_ws, size_t ws_size,
                              hipStream_t stream) {
    const void* h     = d_in[0];
    const void* coord = d_in[1];
    const void* vel   = d_in[2];
    const int* eidx = (const int*)d_in[4];
    float* ws = (float*)d_ws;

    const bool big = ws_size >= (size_t)N_TOTAL * sizeof(float);

    prep_kernel<<<64, 256, 0, stream>>>(d_in[5], d_in[6], d_in[7], d_in[8],
                                        d_in[9], d_in[10], d_in[11], d_in[12],
                                        d_in[13], d_in[14], d_in[15], d_in[16], ws);
    if (big) {
        // zero counters BEFORE the fused pre_edge+count kernel
        hipMemsetAsync((char*)d_ws + (size_t)N_CNT * 4, 0, (size_t)NN * 4, stream);
        // fused: blocks [0,782) = pre_edge MFMA; blocks [782, 782+3125) = count
        pre_edge_kernel<<<PRE_BLOCKS + (NE + 255) / 256, 256, 0, stream>>>(h, eidx, ws);
        scan_kernel<<<1, 1024, 0, stream>>>(ws);
        scatter_kernel<<<(NE + 255) / 256, 256, 0, stream>>>(eidx, ws);
        edge_csr_kernel<<<1024, 256, 0, stream>>>(coord, ws);
        node_kernel_csr<<<782, 256, 0, stream>>>(h, coord, vel, ws, d_out);
    } else {
        pre_edge_kernel<<<PRE_BLOCKS, 256, 0, stream>>>(h, eidx, ws);
        hipMemsetAsync((char*)d_ws + (size_t)F_AGGH * 4, 0,
                       (size_t)(F_TOTAL - F_AGGH) * 4, stream);
        edge_atomic_kernel<<<(NE + 255) / 256, 256, 0, stream>>>(coord, eidx, ws);
        node_kernel_atomic<<<(NN + 255) / 256, 256, 0, stream>>>(h, coord, vel, ws, d_out);
    }
}

// Round 16
// 336.095 us; speedup vs baseline: 1.3036x; 1.0249x over previous
//
#include <hip/hip_runtime.h>
#include <hip/hip_bf16.h>
#include <stdint.h>

#define NE 800000
#define NN 50000
#define PRE_BLOCKS 782   // pre_edge blocks (3125 chunks / 4 waves); count blocks follow

// ---- weight region (float offsets). O_W2 / O_WN2 / O_WC1T hold TRANSPOSED weights.
#define O_W1   0          // We1  [129*64] row-major
#define O_B1   8256
#define O_W2   8320       // We2^T [64*64]
#define O_B2   12416
#define O_WC1  12480      // Wc1  [64*64] row-major (atomic-fallback scalar path)
#define O_BC1  16576
#define O_WC2  16640
#define O_BC2  16704
#define O_WN1  16768      // Wn1  [128*64] row-major
#define O_BN1  24960
#define O_WN2  25024      // Wn2^T [64*64]
#define O_BN2  29120
#define O_FLAG 29184      // int: 1 = tensors bf16, 0 = f32 (written by prep)
#define O_WC1T 29248      // Wc1^T [64*64] (MFMA path)

// ---- per-node layer-1 precompute (fp32):
// Y[n][0:64]=h[n]@We1[0:64] + b1 (b1 folded), Y[n][64:128]=h[n]@We1[64:128]
#define O_Y    33344                    // float [NN*128]
#define Y_END  (O_Y + NN*128)

// ---- CSR layout. N_RC holds col-only (int[NE]); ef16/tr regions unused
// (agg fused into edge kernel) but kept in the layout for ws-size gating.
#define N_OFF   Y_END                   // int off[NN+1] (padded to 50008)
#define N_CNT   (N_OFF + 50008)         // int count/cursor[NN]
#define N_RC    (N_CNT + NN)            // int col[NE] by position
#define N_AGGH  (N_RC + 2*NE)           // float [NN*64]
#define N_SUMT  (N_AGGH + NN*64)        // float [NN*3]
#define N_EF16  (N_SUMT + NN*3 + 2)     // (unused)
#define N_TR    (N_EF16 + NE*32)        // (unused)
#define N_TOTAL (N_TR + NE*3)           // ~39.5M words ~ 158 MB (ws gate)

// ---- atomic fallback layout ----
#define F_AGGH  Y_END
#define F_SUMT  (F_AGGH + NN*64)
#define F_CNT   (F_SUMT + NN*3)
#define F_TOTAL (F_CNT + NN)

#define OUT_COORD (NN*64)
#define OUT_V     (NN*64 + NN*3)

typedef __attribute__((ext_vector_type(8))) short bf16x8;
typedef __attribute__((ext_vector_type(4))) short bf16x4;
typedef __attribute__((ext_vector_type(4))) float f32x4;

static __device__ __forceinline__ float bf2f(const __hip_bfloat16 x) { return __bfloat162float(x); }

template<bool B16>
static __device__ __forceinline__ float ldf(const void* p, size_t i) {
    if (B16) return __bfloat162float(((const __hip_bfloat16*)p)[i]);
    else     return ((const float*)p)[i];
}
template<bool B16>
static __device__ __forceinline__ void stf(void* p, size_t i, float v) {
    if (B16) ((__hip_bfloat16*)p)[i] = __float2bfloat16(v);
    else     ((float*)p)[i] = v;
}
template<bool B16>
static __device__ __forceinline__ float4 ld4(const void* p, size_t i4) {
    if (B16) {
        uint2 u = ((const uint2*)p)[i4];
        return make_float4(__uint_as_float(u.x << 16), __uint_as_float(u.x & 0xffff0000u),
                           __uint_as_float(u.y << 16), __uint_as_float(u.y & 0xffff0000u));
    } else {
        return ((const float4*)p)[i4];
    }
}
template<bool B16>
static __device__ __forceinline__ void st4(void* p, size_t i4, float4 v) {
    if (B16) {
        stf<true>(p, 4*i4 + 0, v.x); stf<true>(p, 4*i4 + 1, v.y);
        stf<true>(p, 4*i4 + 2, v.z); stf<true>(p, 4*i4 + 3, v.w);
    } else {
        ((float4*)p)[i4] = v;
    }
}
static __device__ __forceinline__ unsigned short f2bf_bits(float x) {
    __hip_bfloat16 b = __float2bfloat16(x);
    return *reinterpret_cast<unsigned short*>(&b);
}
static __device__ __forceinline__ uint32_t pack_bf2(float lo, float hi) {
    return (uint32_t)f2bf_bits(lo) | ((uint32_t)f2bf_bits(hi) << 16);
}
static __device__ __forceinline__ short bfs(float x) {
    unsigned short u = f2bf_bits(x);
    return *reinterpret_cast<short*>(&u);
}
// runtime-dtype vector load/store (isb: 1 = tensors bf16, 0 = f32)
static __device__ __forceinline__ float4 ld4rt(const void* p, size_t i4, int isb) {
    if (isb) {
        uint2 u = ((const uint2*)p)[i4];
        return make_float4(__uint_as_float(u.x << 16), __uint_as_float(u.x & 0xffff0000u),
                           __uint_as_float(u.y << 16), __uint_as_float(u.y & 0xffff0000u));
    }
    return ((const float4*)p)[i4];
}
static __device__ __forceinline__ void st4rt(void* p, size_t i4, float4 v, int isb) {
    if (isb) {
        ((uint2*)p)[i4] = make_uint2(pack_bf2(v.x, v.y), pack_bf2(v.z, v.w));
    } else {
        ((float4*)p)[i4] = v;
    }
}

static __device__ __forceinline__ f32x4 mfma32(bf16x8 a, bf16x8 b, f32x4 c) {
    return __builtin_amdgcn_mfma_f32_16x16x32_bf16(a, b, c, 0, 0, 0);
}
static __device__ __forceinline__ f32x4 mfma16(bf16x4 a, bf16x4 b, f32x4 c) {
#if defined(__has_builtin)
#if __has_builtin(__builtin_amdgcn_mfma_f32_16x16x16bf16_1k)
    return __builtin_amdgcn_mfma_f32_16x16x16bf16_1k(a, b, c, 0, 0, 0);
#define MFMA16_DONE 1
#endif
#endif
#ifndef MFMA16_DONE
    asm volatile("v_mfma_f32_16x16x16_bf16 %0, %1, %2, %0\n\ts_nop 7\n\ts_nop 7"
                 : "+v"(c) : "v"(a), "v"(b));
    return c;
#endif
}

// ---- inline dtype sniff (each prep thread recomputes locally; L1-broadcast.
// P(wrong) ~ 0.48^128.)
static __device__ __forceinline__ int sniff_isb(const uint32_t* __restrict__ w) {
    int bad = 0;
    for (int i = 0; i < 128; ++i) {
        uint32_t d = w[i];
        float a = __uint_as_float(d << 16);
        float b = __uint_as_float(d & 0xffff0000u);
        if (!(fabsf(a) <= 0.1f)) bad++;
        if (!(fabsf(b) <= 0.1f)) bad++;
    }
    return (bad == 0) ? 1 : 0;
}

// ---- weights -> fp32 in ws; W2/Wn2/WC1T transposed. Writes O_FLAG.
__global__ void prep_kernel(
    const void* We1, const void* be1, const void* We2, const void* be2,
    const void* Wn1, const void* bn1, const void* Wn2, const void* bn2,
    const void* Wc1, const void* bc1, const void* Wc2, const void* bc2,
    float* __restrict__ wf)
{
    const int isb = sniff_isb((const uint32_t*)We1);
    int tid = blockIdx.x * blockDim.x + threadIdx.x;
    int stride = gridDim.x * blockDim.x;
    if (tid == 0) ((int*)wf)[O_FLAG] = isb;        // for downstream kernels
#define LD(src, i) (isb ? bf2f(((const __hip_bfloat16*)(src))[i]) : ((const float*)(src))[i])
#define CP(dst, src, n)  for (int i = tid; i < (n); i += stride) wf[(dst) + i] = LD(src, i);
#define CPT(dst, src)    for (int i = tid; i < 4096; i += stride) \
        wf[(dst) + (i & 63) * 64 + (i >> 6)] = LD(src, i);
    CP(O_W1,  We1, 129*64)  CP(O_B1,  be1, 64)
    CPT(O_W2,  We2)         CP(O_B2,  be2, 64)
    CP(O_WC1, Wc1, 64*64)   CP(O_BC1, bc1, 64)
    CPT(O_WC1T, Wc1)
    CP(O_WC2, Wc2, 64)      CP(O_BC2, bc2, 1)
    CP(O_WN1, Wn1, 128*64)  CP(O_BN1, bn1, 64)
    CPT(O_WN2, Wn2)         CP(O_BN2, bn2, 64)
#undef CP
#undef CPT
#undef LD
}

// ---- R11 (HW-verified): MFMA pre_edge — Y^T = We1^T @ h^T (+b1 on row half).
// R15: count_kernel fused in — blocks >= PRE_BLOCKS histogram edge rows and
// exit before any LDS work (block-uniform branch; no barrier hazard).
__global__ __launch_bounds__(256, 3) void pre_edge_kernel(
    const void* __restrict__ h, const int* __restrict__ ei, float* __restrict__ ws)
{
    if (blockIdx.x >= PRE_BLOCKS) {                // fused count (CSR path only)
        int e = (blockIdx.x - PRE_BLOCKS) * 256 + threadIdx.x;
        if (e < NE) atomicAdd((int*)ws + N_CNT + ei[e], 1);
        return;
    }

    const int isb = ((const int*)ws)[O_FLAG];
    __shared__ bf16x8 s_wh[16][64];                // We1^T frags [2t+s][lane]
    __shared__ bf16x8 s_wl[16][64];
    __shared__ __align__(16) float s_b1[64];

    const int tid = threadIdx.x;
    for (int f = tid; f < 1024; f += 256) {
        int frag = f >> 6, l = f & 63;
        int t = frag >> 1, s = frag & 1, e2 = l & 15, g2 = l >> 4;
        const float* p = ws + O_W1 + (size_t)((t >= 4 ? 64 : 0) + 32*s + 8*g2) * 64
                         + 16*(t & 3) + e2;
        bf16x8 rh, rl;
        #pragma unroll
        for (int j = 0; j < 8; ++j) {
            float w = p[j * 64];
            unsigned short hb = f2bf_bits(w);
            rh[j] = (short)hb;
            rl[j] = bfs(w - __uint_as_float((uint32_t)hb << 16));
        }
        s_wh[frag][l] = rh; s_wl[frag][l] = rl;
    }
    for (int i = tid; i < 64; i += 256) s_b1[i] = ws[O_B1 + i];
    __syncthreads();

    const int lane = tid & 63, e = lane & 15, g = lane >> 4;
    const int c = blockIdx.x * 4 + (tid >> 6);
    if (c >= NN / 16) return;
    asm volatile("" ::: "memory");                 // keep LDS reads below (R8 lesson)
    const int n = c * 16 + e;

    bf16x8 bhi[2], blo[2];
    #pragma unroll
    for (int s = 0; s < 2; ++s) {
        float4 a0 = ld4rt(h, (size_t)n * 16 + 8*s + 2*g, isb);
        float4 a1 = ld4rt(h, (size_t)n * 16 + 8*s + 2*g + 1, isb);
        float a[8] = {a0.x, a0.y, a0.z, a0.w, a1.x, a1.y, a1.z, a1.w};
        bf16x8 h8, l8;
        #pragma unroll
        for (int j = 0; j < 8; ++j) {
            unsigned short hb = f2bf_bits(a[j]);
            h8[j] = (short)hb;
            l8[j] = bfs(a[j] - __uint_as_float((uint32_t)hb << 16));
        }
        bhi[s] = h8; blo[s] = l8;
    }

    #pragma unroll
    for (int t = 0; t < 8; ++t) {
        f32x4 d;
        if (t < 4) d = *(const f32x4*)&s_b1[16*t + 4*g];
        else       d = (f32x4){0.0f, 0.0f, 0.0f, 0.0f};
        #pragma unroll
        for (int s = 0; s < 2; ++s) {
            bf16x8 wh = s_wh[2*t + s][lane];
            bf16x8 wl = s_wl[2*t + s][lane];
            d = mfma32(wh, bhi[s], d);
            d = mfma32(wh, blo[s], d);
            d = mfma32(wl, bhi[s], d);
        }
        *(float4*)(ws + O_Y + (size_t)n * 128 + 16*t + 4*g) =
            make_float4(d[0], d[1], d[2], d[3]);
    }
}

// ---- edge MLP scalar core (atomic-fallback only) ----
template<bool B16>
static __device__ __forceinline__ void edge_mlp(
    const void* __restrict__ coord, const float* __restrict__ wf,
    int row, int col,
    float4 efbuf[16], float& gate, float& cdx, float& cdy, float& cdz)
{
    cdx = ldf<B16>(coord, 3*row + 0) - ldf<B16>(coord, 3*col + 0);
    cdy = ldf<B16>(coord, 3*row + 1) - ldf<B16>(coord, 3*col + 1);
    cdz = ldf<B16>(coord, 3*row + 2) - ldf<B16>(coord, 3*col + 2);
    float radial = cdx*cdx + cdy*cdy + cdz*cdz;

    const float4* yrv = (const float4*)(wf + O_Y + (size_t)row * 128);
    const float4* ycv = (const float4*)(wf + O_Y + (size_t)col * 128 + 64);

    float acc[64];
    #pragma unroll
    for (int q = 0; q < 16; ++q) {
        float4 a = yrv[q];
        float4 b = ycv[q];
        const float* wr = wf + O_W1 + 128 * 64 + q * 4;
        acc[4*q+0] = fmaxf(fmaf(radial, wr[0], a.x + b.x), 0.0f);
        acc[4*q+1] = fmaxf(fmaf(radial, wr[1], a.y + b.y), 0.0f);
        acc[4*q+2] = fmaxf(fmaf(radial, wr[2], a.z + b.z), 0.0f);
        acc[4*q+3] = fmaxf(fmaf(radial, wr[3], a.w + b.w), 0.0f);
    }

    #pragma unroll
    for (int j0 = 0; j0 < 16; ++j0) {
        float c[4];
        #pragma unroll
        for (int u = 0; u < 4; ++u) {
            int j = j0 * 4 + u;
            float t = wf[O_B2 + j];
            const float* w2t = wf + O_W2 + j * 64;
            #pragma unroll
            for (int k = 0; k < 64; ++k) t = fmaf(acc[k], w2t[k], t);
            c[u] = fmaxf(t, 0.0f);
        }
        efbuf[j0] = make_float4(c[0], c[1], c[2], c[3]);
    }

    float hid[64];
    #pragma unroll
    for (int j = 0; j < 64; ++j) hid[j] = wf[O_BC1 + j];
    #pragma unroll
    for (int j0 = 0; j0 < 16; ++j0) {
        float4 ef4 = efbuf[j0];
        const float* w0 = wf + O_WC1 + (j0 * 4 + 0) * 64;
        const float* w1 = wf + O_WC1 + (j0 * 4 + 1) * 64;
        const float* w2 = wf + O_WC1 + (j0 * 4 + 2) * 64;
        const float* w3 = wf + O_WC1 + (j0 * 4 + 3) * 64;
        #pragma unroll
        for (int jj = 0; jj < 64; ++jj) hid[jj] = fmaf(ef4.x, w0[jj], hid[jj]);
        #pragma unroll
        for (int jj = 0; jj < 64; ++jj) hid[jj] = fmaf(ef4.y, w1[jj], hid[jj]);
        #pragma unroll
        for (int jj = 0; jj < 64; ++jj) hid[jj] = fmaf(ef4.z, w2[jj], hid[jj]);
        #pragma unroll
        for (int jj = 0; jj < 64; ++jj) hid[jj] = fmaf(ef4.w, w3[jj], hid[jj]);
    }

    float g0 = wf[O_BC2], g1 = 0.0f, g2 = 0.0f, g3 = 0.0f;
    #pragma unroll
    for (int j = 0; j < 64; j += 4) {
        g0 = fmaf(fmaxf(hid[j + 0], 0.0f), wf[O_WC2 + j + 0], g0);
        g1 = fmaf(fmaxf(hid[j + 1], 0.0f), wf[O_WC2 + j + 1], g1);
        g2 = fmaf(fmaxf(hid[j + 2], 0.0f), wf[O_WC2 + j + 2], g2);
        g3 = fmaf(fmaxf(hid[j + 3], 0.0f), wf[O_WC2 + j + 3], g3);
    }
    gate = (g0 + g1) + (g2 + g3);
}

// ============ CSR path ============
// R12 (HW-verified): 4 elements/thread, 13 iterations.
__global__ __launch_bounds__(1024) void scan_kernel(float* __restrict__ ws) {
    int* cnt = (int*)ws + N_CNT;
    int* off = (int*)ws + N_OFF;
    __shared__ int wsum[16];
    __shared__ int carry_s;
    int tid = threadIdx.x, lane = tid & 63, wid = tid >> 6;
    if (tid == 0) carry_s = 0;
    __syncthreads();
    for (int base = 0; base < NN; base += 4096) {
        int i0 = base + tid * 4;
        int a0 = (i0 + 0 < NN) ? cnt[i0 + 0] : 0;
        int a1 = (i0 + 1 < NN) ? cnt[i0 + 1] : 0;
        int a2 = (i0 + 2 < NN) ? cnt[i0 + 2] : 0;
        int a3 = (i0 + 3 < NN) ? cnt[i0 + 3] : 0;
        int tsum = ((a0 + a1) + (a2 + a3));
        int v = tsum;
        #pragma unroll
        for (int s = 1; s < 64; s <<= 1) { int t = __shfl_up(v, s, 64); if (lane >= s) v += t; }
        if (lane == 63) wsum[wid] = v;
        __syncthreads();
        if (wid == 0) {
            int w = (lane < 16) ? wsum[lane] : 0;
            #pragma unroll
            for (int s = 1; s < 16; s <<= 1) { int t = __shfl_up(w, s, 64); if (lane >= s) w += t; }
            if (lane < 16) wsum[lane] = w;
        }
        __syncthreads();
        int waveback = (wid > 0) ? wsum[wid - 1] : 0;
        int excl = carry_s + waveback + (v - tsum);
        if (i0 + 0 < NN) { off[i0 + 0] = excl; cnt[i0 + 0] = excl; }
        excl += a0;
        if (i0 + 1 < NN) { off[i0 + 1] = excl; cnt[i0 + 1] = excl; }
        excl += a1;
        if (i0 + 2 < NN) { off[i0 + 2] = excl; cnt[i0 + 2] = excl; }
        excl += a2;
        if (i0 + 3 < NN) { off[i0 + 3] = excl; cnt[i0 + 3] = excl; }
        __syncthreads();
        if (tid == 0) carry_s += wsum[15];
        __syncthreads();
    }
    if (threadIdx.x == 0) off[NN] = carry_s;
}

// store col only (4B) — row is implicit in the node-based edge kernel.
__global__ __launch_bounds__(256) void scatter_kernel(
    const int* __restrict__ ei, float* __restrict__ ws)
{
    int e = blockIdx.x * 256 + threadIdx.x;
    if (e >= NE) return;
    int row = ei[e];
    int col = ei[NE + e];
    int pos = atomicAdd((int*)ws + N_CNT + row, 1);
    ((int*)ws + N_RC)[pos] = col;
}

// ---- R16: node-based MFMA edge kernel, FUSED agg.
// R12-proven core; R16 change: the anti-LICM fence moves BELOW the global
// gathers (col/coords/Yc) inside the chunk loop. LDS weight reads stay
// fenced in-loop (no R8/R11 spill recurrence — they still cannot cross any
// fence), but the gathers of chunk i+1 / node n+1 may now overlap chunk i's
// MFMA+VALU tail (R15 profile: latency-bound, VALU 42 / MFMA 17 / HBM 12,
// occupancy lever exhausted per R13/R14).
#define SPLIT1(H, L, IDX, VAL, WI) { \
    float _v = fmaxf(fmaf(radial, s_w1r[WI], (VAL)), 0.0f); \
    unsigned short _hb = f2bf_bits(_v); \
    H[IDX] = (short)_hb; \
    L[IDX] = bfs(_v - __uint_as_float((uint32_t)_hb << 16)); }
#define SPLIT8(H, L, WOFF, V0,V1,V2,V3,V4,V5,V6,V7) \
    SPLIT1(H,L,0,V0,(WOFF)+0) SPLIT1(H,L,1,V1,(WOFF)+1) \
    SPLIT1(H,L,2,V2,(WOFF)+2) SPLIT1(H,L,3,V3,(WOFF)+3) \
    SPLIT1(H,L,4,V4,(WOFF)+4) SPLIT1(H,L,5,V5,(WOFF)+5) \
    SPLIT1(H,L,6,V6,(WOFF)+6) SPLIT1(H,L,7,V7,(WOFF)+7)
#define PHASEB(D, T) { \
    bf16x8 wh0 = s_wbh[2*(T)+0][lane], wh1 = s_wbh[2*(T)+1][lane]; \
    bf16x8 wl0 = s_wbl[2*(T)+0][lane], wl1 = s_wbl[2*(T)+1][lane]; \
    D = mfma32(wh0, ahi0, D); D = mfma32(wh1, ahi1, D); \
    D = mfma32(wh0, alo0, D); D = mfma32(wh1, alo1, D); \
    D = mfma32(wl0, ahi0, D); D = mfma32(wl1, ahi1, D); }
#define EFBLK(D, BQ, A0,A1,A2,A3) { \
    float _e0 = fmaxf(D[0], 0.0f) * vmask; \
    float _e1 = fmaxf(D[1], 0.0f) * vmask; \
    float _e2 = fmaxf(D[2], 0.0f) * vmask; \
    float _e3 = fmaxf(D[3], 0.0f) * vmask; \
    BQ[0] = (short)f2bf_bits(_e0); BQ[1] = (short)f2bf_bits(_e1); \
    BQ[2] = (short)f2bf_bits(_e2); BQ[3] = (short)f2bf_bits(_e3); \
    A0 += _e0; A1 += _e1; A2 += _e2; A3 += _e3; }
#define PHASEC(D, U) { \
    D = mfma16(s_wc[4*(U)+0][lane], bq0, D); \
    D = mfma16(s_wc[4*(U)+1][lane], bq1, D); \
    D = mfma16(s_wc[4*(U)+2][lane], bq2, D); \
    D = mfma16(s_wc[4*(U)+3][lane], bq3, D); }
#define GATEU(D, U) { \
    gp = fmaf(fmaxf(D[0], 0.0f), s_wc2[16*(U) + 4*g + 0], gp); \
    gp = fmaf(fmaxf(D[1], 0.0f), s_wc2[16*(U) + 4*g + 1], gp); \
    gp = fmaf(fmaxf(D[2], 0.0f), s_wc2[16*(U) + 4*g + 2], gp); \
    gp = fmaf(fmaxf(D[3], 0.0f), s_wc2[16*(U) + 4*g + 3], gp); }
#define RED16(M) \
    ag00 += __shfl_xor(ag00,M,64); ag01 += __shfl_xor(ag01,M,64); \
    ag02 += __shfl_xor(ag02,M,64); ag03 += __shfl_xor(ag03,M,64); \
    ag10 += __shfl_xor(ag10,M,64); ag11 += __shfl_xor(ag11,M,64); \
    ag12 += __shfl_xor(ag12,M,64); ag13 += __shfl_xor(ag13,M,64); \
    ag20 += __shfl_xor(ag20,M,64); ag21 += __shfl_xor(ag21,M,64); \
    ag22 += __shfl_xor(ag22,M,64); ag23 += __shfl_xor(ag23,M,64); \
    ag30 += __shfl_xor(ag30,M,64); ag31 += __shfl_xor(ag31,M,64); \
    ag32 += __shfl_xor(ag32,M,64); ag33 += __shfl_xor(ag33,M,64);

__global__ __launch_bounds__(256, 3) void edge_csr_kernel(
    const void* __restrict__ coord, float* __restrict__ ws)
{
    const int isb = ((const int*)ws)[O_FLAG];

    __shared__ bf16x8 s_wbh[8][64];                // We2^T hi frags [2t+s][lane], 8KB
    __shared__ bf16x8 s_wbl[8][64];                // We2^T lo frags, 8KB
    __shared__ bf16x4 s_wc[16][64];                // Wc1^T frags [4u+t][lane], 8KB
    __shared__ __align__(16) float s_b2[64];
    __shared__ __align__(16) float s_bc1[64];
    __shared__ __align__(16) float s_wc2[64];
    __shared__ float s_w1r[64];
    __shared__ float s_bc2v;

    const int tid = threadIdx.x;
    for (int f = tid; f < 512; f += 256) {         // We2^T hi/lo fill
        int frag = f >> 6, l = f & 63;
        int t = frag >> 1, s = frag & 1, e2 = l & 15, g2 = l >> 4;
        const float* p = ws + O_W2 + (16*t + e2)*64 + 32*s + 8*g2;
        bf16x8 rh, rl;
        #pragma unroll
        for (int j = 0; j < 8; ++j) {
            float w = p[j];
            unsigned short hb = f2bf_bits(w);
            rh[j] = (short)hb;
            float hf = __uint_as_float((uint32_t)hb << 16);
            rl[j] = bfs(w - hf);
        }
        s_wbh[frag][l] = rh;
        s_wbl[frag][l] = rl;
    }
    for (int f = tid; f < 1024; f += 256) {        // Wc1^T fill (hi only)
        int frag = f >> 6, l = f & 63;
        int u = frag >> 2, t = frag & 3, e2 = l & 15, g2 = l >> 4;
        const float* p = ws + O_WC1T + (16*u + e2)*64 + 16*t + 4*g2;
        bf16x4 r;
        #pragma unroll
        for (int j = 0; j < 4; ++j) r[j] = bfs(p[j]);
        s_wc[frag][l] = r;
    }
    for (int i = tid; i < 64; i += 256) {
        s_b2[i]  = ws[O_B2 + i];
        s_bc1[i] = ws[O_BC1 + i];
        s_wc2[i] = ws[O_WC2 + i];
        s_w1r[i] = ws[O_W1 + 128*64 + i];          // radial row of We1
    }
    if (tid == 0) s_bc2v = ws[O_BC2];
    __syncthreads();

    const int lane = threadIdx.x & 63;
    const int e = lane & 15, g = lane >> 4;
    const int wid = blockIdx.x * 4 + (int)(threadIdx.x >> 6);
    const int nw = 4096;                           // grid is exactly 1024 blocks
    const int* off = (const int*)ws + N_OFF;
    const int* colA = (const int*)ws + N_RC;
    const float* cf = (const float*)coord;
    const __hip_bfloat16* cbh = (const __hip_bfloat16*)coord;

    for (int n = wid; n < NN; n += nw) {
        const int s0 = off[n], s1 = off[n + 1];

        // node (row) coords — wave-uniform
        float crx, cry, crz;
        if (isb) {
            crx = bf2f(cbh[3*n+0]); cry = bf2f(cbh[3*n+1]); crz = bf2f(cbh[3*n+2]);
        } else {
            crx = cf[3*n+0]; cry = cf[3*n+1]; crz = cf[3*n+2];
        }
        // row-half Y (k = 32s + 8g + j) — uniform across e-lanes; SCALARIZED
        float y00, y01, y02, y03, y04, y05, y06, y07;
        float y10, y11, y12, y13, y14, y15, y16, y17;
        {
            const float4* yr4 = (const float4*)(ws + O_Y + (size_t)n * 128 + 8*g);
            float4 ra = yr4[0], rb = yr4[1];
            y00=ra.x; y01=ra.y; y02=ra.z; y03=ra.w;
            y04=rb.x; y05=rb.y; y06=rb.z; y07=rb.w;
        }
        {
            const float4* yr4 = (const float4*)(ws + O_Y + (size_t)n * 128 + 32 + 8*g);
            float4 ra = yr4[0], rb = yr4[1];
            y10=ra.x; y11=ra.y; y12=ra.z; y13=ra.w;
            y14=rb.x; y15=rb.y; y16=rb.z; y17=rb.w;
        }

        // SCALARIZED accumulators (rule #20 hard-proofing)
        float ag00=0.f, ag01=0.f, ag02=0.f, ag03=0.f;
        float ag10=0.f, ag11=0.f, ag12=0.f, ag13=0.f;
        float ag20=0.f, ag21=0.f, ag22=0.f, ag23=0.f;
        float ag30=0.f, ag31=0.f, ag32=0.f, ag33=0.f;
        float tx = 0.0f, ty = 0.0f, tz = 0.0f;

        for (int base = s0; base < s1; base += 16) {
            const int cnt = s1 - base;             // >= 1 here
            const bool valid = e < cnt;
            const int col = colA[base + (valid ? e : 0)];

            // issue ALL global gathers for this chunk BEFORE the fence
            float ccx, ccy, ccz;
            if (isb) {
                ccx = bf2f(cbh[3*col+0]); ccy = bf2f(cbh[3*col+1]); ccz = bf2f(cbh[3*col+2]);
            } else {
                ccx = cf[3*col+0]; ccy = cf[3*col+1]; ccz = cf[3*col+2];
            }
            const float* Yc = ws + O_Y + (size_t)col * 128 + 64;
            float4 ca0, cb0, ca1, cb1;
            {
                const float4* yc4 = (const float4*)(Yc + 8*g);
                ca0 = yc4[0]; cb0 = yc4[1];
            }
            {
                const float4* yc4 = (const float4*)(Yc + 32 + 8*g);
                ca1 = yc4[0]; cb1 = yc4[1];
            }

            // anti-LICM fence: LDS weight reads (PHASEB/PHASEC) stay below a
            // fence in every iteration (R12-proven spill guard), while the
            // gathers above may overlap the previous chunk's compute.
            asm volatile("" ::: "memory");

            float cdx = crx - ccx, cdy = cry - ccy, cdz = crz - ccz;
            float radial = cdx*cdx + cdy*cdy + cdz*cdz;

            // acc (k = 32s + 8g + j) in fp32, split hi/lo bf16 — SCALARIZED
            bf16x8 ahi0, alo0, ahi1, alo1;
            SPLIT8(ahi0, alo0, 8*g,
                   y00+ca0.x, y01+ca0.y, y02+ca0.z, y03+ca0.w,
                   y04+cb0.x, y05+cb0.y, y06+cb0.z, y07+cb0.w)
            SPLIT8(ahi1, alo1, 32 + 8*g,
                   y10+ca1.x, y11+ca1.y, y12+ca1.z, y13+ca1.w,
                   y14+cb1.x, y15+cb1.y, y16+cb1.z, y17+cb1.w)

            // phase B: D1[ef][edge], C-init = b2; 3-product hi/lo
            f32x4 d10 = *(const f32x4*)&s_b2[ 0 + 4*g];
            f32x4 d11 = *(const f32x4*)&s_b2[16 + 4*g];
            f32x4 d12 = *(const f32x4*)&s_b2[32 + 4*g];
            f32x4 d13 = *(const f32x4*)&s_b2[48 + 4*g];
            PHASEB(d10, 0) PHASEB(d11, 1) PHASEB(d12, 2) PHASEB(d13, 3)

            // relu (fp32) + validity mask; bq = bf16(ef) for the gate path
            const float vmask = valid ? 1.0f : 0.0f;
            bf16x4 bq0, bq1, bq2, bq3;
            EFBLK(d10, bq0, ag00, ag01, ag02, ag03)
            EFBLK(d11, bq1, ag10, ag11, ag12, ag13)
            EFBLK(d12, bq2, ag20, ag21, ag22, ag23)
            EFBLK(d13, bq3, ag30, ag31, ag32, ag33)

            // phase C: D2[hid][edge] = Wc1^T @ ef^T, C-init = bc1
            f32x4 d20 = *(const f32x4*)&s_bc1[ 0 + 4*g];
            f32x4 d21 = *(const f32x4*)&s_bc1[16 + 4*g];
            f32x4 d22 = *(const f32x4*)&s_bc1[32 + 4*g];
            f32x4 d23 = *(const f32x4*)&s_bc1[48 + 4*g];
            PHASEC(d20, 0) PHASEC(d21, 1) PHASEC(d22, 2) PHASEC(d23, 3)

            // gate = bc2 + sum_h relu(hid[h]) * Wc2[h]; reduce over 4 g-groups
            float gp = 0.0f;
            GATEU(d20, 0) GATEU(d21, 1) GATEU(d22, 2) GATEU(d23, 3)
            gp += __shfl_xor(gp, 16, 64);
            gp += __shfl_xor(gp, 32, 64);
            float gate = gp + s_bc2v;

            if (valid && g == 0) {
                tx += fminf(fmaxf(cdx * gate, -100.0f), 100.0f);
                ty += fminf(fmaxf(cdy * gate, -100.0f), 100.0f);
                tz += fminf(fmaxf(cdz * gate, -100.0f), 100.0f);
            }
        }

        // cross-edge reduce of agg (over e-lanes, within each g-group)
        RED16(1) RED16(2) RED16(4) RED16(8)

        // write agg row: lane (e=t, g) stores features 16t+4g+{0..3}
        float* aggw = ws + N_AGGH + (size_t)n * 64;
        if (e == 0)      *(float4*)(aggw + 0  + 4*g) = make_float4(ag00, ag01, ag02, ag03);
        else if (e == 1) *(float4*)(aggw + 16 + 4*g) = make_float4(ag10, ag11, ag12, ag13);
        else if (e == 2) *(float4*)(aggw + 32 + 4*g) = make_float4(ag20, ag21, ag22, ag23);
        else if (e == 3) *(float4*)(aggw + 48 + 4*g) = make_float4(ag30, ag31, ag32, ag33);

        // cross-edge reduce of trans (g==0 lanes hold partials)
        tx += __shfl_xor(tx, 1, 64); ty += __shfl_xor(ty, 1, 64); tz += __shfl_xor(tz, 1, 64);
        tx += __shfl_xor(tx, 2, 64); ty += __shfl_xor(ty, 2, 64); tz += __shfl_xor(tz, 2, 64);
        tx += __shfl_xor(tx, 4, 64); ty += __shfl_xor(ty, 4, 64); tz += __shfl_xor(tz, 4, 64);
        tx += __shfl_xor(tx, 8, 64); ty += __shfl_xor(ty, 8, 64); tz += __shfl_xor(tz, 8, 64);
        if (lane == 0) {
            ws[N_SUMT + 3*(size_t)n + 0] = tx;
            ws[N_SUMT + 3*(size_t)n + 1] = ty;
            ws[N_SUMT + 3*(size_t)n + 2] = tz;
        }
    }
}
#undef SPLIT1
#undef SPLIT8
#undef PHASEB
#undef EFBLK
#undef PHASEC
#undef GATEU
#undef RED16

// ---- scalar node core (atomic fallback only) ----
template<bool B16>
static __device__ __forceinline__ void node_core(
    const void* __restrict__ h, const void* __restrict__ coord,
    const void* __restrict__ vel, const float* __restrict__ ws,
    const float* __restrict__ agg, const float* __restrict__ sumt, float cntf,
    void* __restrict__ out, int n)
{
    float inv = (cntf > 0.0f) ? (1.0f / fmaxf(cntf, 1.0f)) : 0.0f;
    #pragma unroll
    for (int i = 0; i < 3; ++i) {
        float aggc = sumt[3*n + i] * inv;
        float v = ldf<B16>(vel, 3*n + i) + aggc * 0.125f;
        float cn = ldf<B16>(coord, 3*n + i) + v * 0.125f;
        stf<B16>(out, OUT_COORD + 3*n + i, cn);
        stf<B16>(out, OUT_V + 3*n + i, v);
    }

    float acc[64];
    #pragma unroll
    for (int j = 0; j < 64; ++j) acc[j] = ws[O_BN1 + j];

    #pragma unroll 4
    for (int q = 0; q < 16; ++q) {
        float4 a = ld4<B16>(h, (size_t)n * 16 + q);
        const float* w = ws + O_WN1 + (q * 4) * 64;
        #pragma unroll
        for (int j = 0; j < 64; ++j) acc[j] = fmaf(a.x, w[j], acc[j]);
        #pragma unroll
        for (int j = 0; j < 64; ++j) acc[j] = fmaf(a.y, w[64 + j], acc[j]);
        #pragma unroll
        for (int j = 0; j < 64; ++j) acc[j] = fmaf(a.z, w[128 + j], acc[j]);
        #pragma unroll
        for (int j = 0; j < 64; ++j) acc[j] = fmaf(a.w, w[192 + j], acc[j]);
    }
    const float4* agv = (const float4*)(agg + (size_t)n * 64);
    #pragma unroll 4
    for (int q = 0; q < 16; ++q) {
        float4 a = agv[q];
        const float* w = ws + O_WN1 + (64 + q * 4) * 64;
        #pragma unroll
        for (int j = 0; j < 64; ++j) acc[j] = fmaf(a.x, w[j], acc[j]);
        #pragma unroll
        for (int j = 0; j < 64; ++j) acc[j] = fmaf(a.y, w[64 + j], acc[j]);
        #pragma unroll
        for (int j = 0; j < 64; ++j) acc[j] = fmaf(a.z, w[128 + j], acc[j]);
        #pragma unroll
        for (int j = 0; j < 64; ++j) acc[j] = fmaf(a.w, w[192 + j], acc[j]);
    }
    #pragma unroll
    for (int j = 0; j < 64; ++j) acc[j] = fmaxf(acc[j], 0.0f);

    float4 ob[16];
    #pragma unroll
    for (int j0 = 0; j0 < 16; ++j0) {
        float4 hres = ld4<B16>(h, (size_t)n * 16 + j0);
        float c[4];
        #pragma unroll
        for (int u = 0; u < 4; ++u) {
            int j = j0 * 4 + u;
            float t = ws[O_BN2 + j];
            const float* w = ws + O_WN2 + j * 64;
            #pragma unroll
            for (int k = 0; k < 64; ++k) t = fmaf(acc[k], w[k], t);
            c[u] = t;
        }
        ob[j0] = make_float4(hres.x + c[0], hres.y + c[1], hres.z + c[2], hres.w + c[3]);
    }
    #pragma unroll
    for (int j0 = 0; j0 < 16; ++j0) st4<B16>(out, (size_t)n * 16 + j0, ob[j0]);
}

// ---- R11 (HW-verified): MFMA node kernel (CSR path, both dtypes).
__global__ __launch_bounds__(256, 3) void node_kernel_csr(
    const void* __restrict__ h, const void* __restrict__ coord,
    const void* __restrict__ vel, const float* __restrict__ ws,
    void* __restrict__ out)
{
    const int isb = ((const int*)ws)[O_FLAG];

    __shared__ bf16x8 s_w1h[16][64];               // Wn1^T frags [4t+s][lane], 16KB
    __shared__ bf16x8 s_w1l[16][64];               // 16KB
    __shared__ bf16x4 s_w2h[16][64];               // Wn2^T frags [4u+t][lane], 8KB
    __shared__ bf16x4 s_w2l[16][64];               // 8KB
    __shared__ __align__(16) float s_bn1[64];
    __shared__ __align__(16) float s_bn2[64];

    const int tid = threadIdx.x;
    for (int f = tid; f < 1024; f += 256) {        // Wn1^T hi/lo fill
        int frag = f >> 6, l = f & 63;
        int t = frag >> 2, s = frag & 3, e2 = l & 15, g2 = l >> 4;
        const float* p = ws + O_WN1 + (size_t)(32*s + 8*g2) * 64 + 16*t + e2;
        bf16x8 rh, rl;
        #pragma unroll
        for (int j = 0; j < 8; ++j) {
            float w = p[j * 64];
            unsigned short hb = f2bf_bits(w);
            rh[j] = (short)hb;
            rl[j] = bfs(w - __uint_as_float((uint32_t)hb << 16));
        }
        s_w1h[frag][l] = rh; s_w1l[frag][l] = rl;
    }
    for (int f = tid; f < 1024; f += 256) {        // Wn2^T hi/lo fill
        int frag = f >> 6, l = f & 63;
        int u = frag >> 2, t = frag & 3, e2 = l & 15, g2 = l >> 4;
        const float* p = ws + O_WN2 + (16*u + e2) * 64 + 16*t + 4*g2;
        bf16x4 rh, rl;
        #pragma unroll
        for (int j = 0; j < 4; ++j) {
            float w = p[j];
            unsigned short hb = f2bf_bits(w);
            rh[j] = (short)hb;
            rl[j] = bfs(w - __uint_as_float((uint32_t)hb << 16));
        }
        s_w2h[frag][l] = rh; s_w2l[frag][l] = rl;
    }
    for (int i = tid; i < 64; i += 256) { s_bn1[i] = ws[O_BN1 + i]; s_bn2[i] = ws[O_BN2 + i]; }
    __syncthreads();

    const int lane = tid & 63, e = lane & 15, g = lane >> 4;
    const int c = blockIdx.x * 4 + (tid >> 6);
    if (c >= NN / 16) return;
    asm volatile("" ::: "memory");                 // anti-LICM
    const int n = c * 16 + e;

    // coord / vel epilogue on g==0 lanes
    if (g == 0) {
        const int* off = (const int*)ws + N_OFF;
        float cntf = (float)(off[n + 1] - off[n]);
        float inv = (cntf > 0.0f) ? (1.0f / fmaxf(cntf, 1.0f)) : 0.0f;
        #pragma unroll
        for (int i = 0; i < 3; ++i) {
            float aggc = ws[N_SUMT + 3*n + i] * inv;
            float vv, cc;
            if (isb) {
                vv = bf2f(((const __hip_bfloat16*)vel)[3*n + i]);
                cc = bf2f(((const __hip_bfloat16*)coord)[3*n + i]);
            } else {
                vv = ((const float*)vel)[3*n + i];
                cc = ((const float*)coord)[3*n + i];
            }
            float v = vv + aggc * 0.125f;
            float cn = cc + v * 0.125f;
            if (isb) {
                ((__hip_bfloat16*)out)[OUT_COORD + 3*n + i] = __float2bfloat16(cn);
                ((__hip_bfloat16*)out)[OUT_V + 3*n + i] = __float2bfloat16(v);
            } else {
                ((float*)out)[OUT_COORD + 3*n + i] = cn;
                ((float*)out)[OUT_V + 3*n + i] = v;
            }
        }
    }

    // B-op: K=128 = h[0:64] ++ agg[0:64], hi/lo split (k = 32s + 8g + j)
    bf16x8 bhi[4], blo[4];
    #pragma unroll
    for (int s = 0; s < 4; ++s) {
        float a[8];
        if (s < 2) {
            float4 a0 = ld4rt(h, (size_t)n * 16 + 8*s + 2*g, isb);
            float4 a1 = ld4rt(h, (size_t)n * 16 + 8*s + 2*g + 1, isb);
            a[0]=a0.x; a[1]=a0.y; a[2]=a0.z; a[3]=a0.w;
            a[4]=a1.x; a[5]=a1.y; a[6]=a1.z; a[7]=a1.w;
        } else {
            const float4* ag = (const float4*)(ws + N_AGGH + (size_t)n * 64);
            float4 a0 = ag[8*(s-2) + 2*g];
            float4 a1 = ag[8*(s-2) + 2*g + 1];
            a[0]=a0.x; a[1]=a0.y; a[2]=a0.z; a[3]=a0.w;
            a[4]=a1.x; a[5]=a1.y; a[6]=a1.z; a[7]=a1.w;
        }
        bf16x8 h8, l8;
        #pragma unroll
        for (int j = 0; j < 8; ++j) {
            unsigned short hb = f2bf_bits(a[j]);
            h8[j] = (short)hb;
            l8[j] = bfs(a[j] - __uint_as_float((uint32_t)hb << 16));
        }
        bhi[s] = h8; blo[s] = l8;
    }

    // N1 (3-product hi/lo)
    f32x4 d1[4];
    #pragma unroll
    for (int t = 0; t < 4; ++t) d1[t] = *(const f32x4*)&s_bn1[16*t + 4*g];
    #pragma unroll
    for (int t = 0; t < 4; ++t) {
        #pragma unroll
        for (int s = 0; s < 4; ++s) {
            bf16x8 wh = s_w1h[4*t + s][lane];
            bf16x8 wl = s_w1l[4*t + s][lane];
            d1[t] = mfma32(wh, bhi[s], d1[t]);
            d1[t] = mfma32(wh, blo[s], d1[t]);
            d1[t] = mfma32(wl, bhi[s], d1[t]);
        }
    }

    // relu -> hi/lo fragments (features 16t+4g+{0..3})
    bf16x4 rhi[4], rlo[4];
    #pragma unroll
    for (int t = 0; t < 4; ++t) {
        #pragma unroll
        for (int j = 0; j < 4; ++j) {
            float v = fmaxf(d1[t][j], 0.0f);
            unsigned short hb = f2bf_bits(v);
            rhi[t][j] = (short)hb;
            rlo[t][j] = bfs(v - __uint_as_float((uint32_t)hb << 16));
        }
    }

    // N2 (3-product)
    f32x4 d2[4];
    #pragma unroll
    for (int u = 0; u < 4; ++u) d2[u] = *(const f32x4*)&s_bn2[16*u + 4*g];
    #pragma unroll
    for (int u = 0; u < 4; ++u) {
        #pragma unroll
        for (int t = 0; t < 4; ++t) {
            bf16x4 wh = s_w2h[4*u + t][lane];
            bf16x4 wl = s_w2l[4*u + t][lane];
            d2[u] = mfma16(wh, rhi[t], d2[u]);
            d2[u] = mfma16(wh, rlo[t], d2[u]);
            d2[u] = mfma16(wl, rhi[t], d2[u]);
        }
    }

    // residual + store (features 16u+4g+{0..3} -> float4 at h[n][16u+4g])
    #pragma unroll
    for (int u = 0; u < 4; ++u) {
        float4 hres = ld4rt(h, (size_t)n * 16 + 4*u + g, isb);
        float4 o = make_float4(hres.x + d2[u][0], hres.y + d2[u][1],
                               hres.z + d2[u][2], hres.w + d2[u][3]);
        st4rt(out, (size_t)n * 16 + 4*u + g, o, isb);
    }
}

// ============ atomic fallback (small ws) ============
template<bool B16>
static __device__ __forceinline__ void edge_atomic_core(
    const void* __restrict__ coord, const int* __restrict__ ei,
    float* __restrict__ ws, int e)
{
    int row = ei[e];
    int col = ei[NE + e];
    float gate, cdx, cdy, cdz;
    float4 efbuf[16];
    edge_mlp<B16>(coord, ws, row, col, efbuf, gate, cdx, cdy, cdz);

    float* ah = ws + F_AGGH + (size_t)row * 64;
    #pragma unroll
    for (int q = 0; q < 16; ++q) {
        unsafeAtomicAdd(&ah[4*q + 0], efbuf[q].x);
        unsafeAtomicAdd(&ah[4*q + 1], efbuf[q].y);
        unsafeAtomicAdd(&ah[4*q + 2], efbuf[q].z);
        unsafeAtomicAdd(&ah[4*q + 3], efbuf[q].w);
    }
    unsafeAtomicAdd(&ws[F_SUMT + 3*row + 0], fminf(fmaxf(cdx * gate, -100.0f), 100.0f));
    unsafeAtomicAdd(&ws[F_SUMT + 3*row + 1], fminf(fmaxf(cdy * gate, -100.0f), 100.0f));
    unsafeAtomicAdd(&ws[F_SUMT + 3*row + 2], fminf(fmaxf(cdz * gate, -100.0f), 100.0f));
    unsafeAtomicAdd(&ws[F_CNT + row], 1.0f);
}

__global__ __launch_bounds__(256, 2) void edge_atomic_kernel(
    const void* __restrict__ coord, const int* __restrict__ ei,
    float* __restrict__ ws)
{
    int e = blockIdx.x * 256 + threadIdx.x;
    if (e >= NE) return;
    if (((const int*)ws)[O_FLAG]) edge_atomic_core<true>(coord, ei, ws, e);
    else                          edge_atomic_core<false>(coord, ei, ws, e);
}

__global__ __launch_bounds__(256, 2) void node_kernel_atomic(
    const void* __restrict__ h, const void* __restrict__ coord,
    const void* __restrict__ vel, const float* __restrict__ ws,
    void* __restrict__ out)
{
    int n = blockIdx.x * 256 + threadIdx.x;
    if (n >= NN) return;
    float cntf = ws[F_CNT + n];
    if (((const int*)ws)[O_FLAG])
        node_core<true>(h, coord, vel, ws, ws + F_AGGH, ws + F_SUMT, cntf, out, n);
    else
        node_core<false>(h, coord, vel, ws, ws + F_AGGH, ws + F_SUMT, cntf, out, n);
}

extern "C" void kernel_launch(void* const* d_in, const int* in_sizes, int n_in,
                              void* d_out, int out_size, void* d_ws, size_t ws_size,
                              hipStream_t stream) {
    const void* h     = d_in[0];
    const void* coord = d_in[1];
    const void* vel   = d_in[2];
    const int* eidx = (const int*)d_in[4];
    float* ws = (float*)d_ws;

    const bool big = ws_size >= (size_t)N_TOTAL * sizeof(float);

    prep_kernel<<<64, 256, 0, stream>>>(d_in[5], d_in[6], d_in[7], d_in[8],
                                        d_in[9], d_in[10], d_in[11], d_in[12],
                                        d_in[13], d_in[14], d_in[15], d_in[16], ws);
    if (big) {
        // zero counters BEFORE the fused pre_edge+count kernel
        hipMemsetAsync((char*)d_ws + (size_t)N_CNT * 4, 0, (size_t)NN * 4, stream);
        // fused: blocks [0,782) = pre_edge MFMA; blocks [782, 782+3125) = count
        pre_edge_kernel<<<PRE_BLOCKS + (NE + 255) / 256, 256, 0, stream>>>(h, eidx, ws);
        scan_kernel<<<1, 1024, 0, stream>>>(ws);
        scatter_kernel<<<(NE + 255) / 256, 256, 0, stream>>>(eidx, ws);
        edge_csr_kernel<<<1024, 256, 0, stream>>>(coord, ws);
        node_kernel_csr<<<782, 256, 0, stream>>>(h, coord, vel, ws, d_out);
    } else {
        pre_edge_kernel<<<PRE_BLOCKS, 256, 0, stream>>>(h, eidx, ws);
        hipMemsetAsync((char*)d_ws + (size_t)F_AGGH * 4, 0,
                       (size_t)(F_TOTAL - F_AGGH) * 4, stream);
        edge_atomic_kernel<<<(NE + 255) / 256, 256, 0, stream>>>(coord, eidx, ws);
        node_kernel_atomic<<<(NN + 255) / 256, 256, 0, stream>>>(h, coord, vel, ws, d_out);
    }
}